// Round 1
// baseline (555.731 us; speedup 1.0000x reference)
//
#include <hip/hip_runtime.h>

#define N_NODES 50000
#define N_EDGES 800000
#define F_IN    32
#define F_OUT   64
#define PERIODS 12
#define C_FEAT  160   // [X, Tx1o, Tx1i, Tx2o, Tx2i] each 32 channels

// ---------------------------------------------------------------------------
// Weighted degrees: deg_out[row] += w, deg_in[col] += w
// ---------------------------------------------------------------------------
__global__ __launch_bounds__(256) void k_deg(const int* __restrict__ ei,
                                             const float* __restrict__ ew,
                                             float* __restrict__ deg_out,
                                             float* __restrict__ deg_in) {
    int e = blockIdx.x * blockDim.x + threadIdx.x;
    if (e >= N_EDGES) return;
    int r = ei[e];
    int c = ei[N_EDGES + e];
    float w = ew[e];
    unsafeAtomicAdd(deg_out + r, w);
    unsafeAtomicAdd(deg_in + c, w);
}

__global__ __launch_bounds__(256) void k_inv(float* __restrict__ deg_out,
                                             float* __restrict__ deg_in) {
    int v = blockIdx.x * blockDim.x + threadIdx.x;
    if (v >= N_NODES) return;
    deg_out[v] = 1.0f / deg_out[v];
    deg_in[v]  = 1.0f / deg_in[v];
}

// ---------------------------------------------------------------------------
// One diffusion step, both directions fused.
//   out_fwd[col] += inv_o[row] * h_fwd[row]   (prop_fwd)
//   out_rev[row] += inv_i[col] * h_rev[col]   (prop_rev)
// thread = (edge, feature): 32 consecutive lanes share an edge -> coalesced
// 128B gathers and 128B contiguous atomic bursts.
// ---------------------------------------------------------------------------
__global__ __launch_bounds__(256) void k_prop(const int* __restrict__ ei,
                                              const float* __restrict__ inv_o,
                                              const float* __restrict__ inv_i,
                                              const float* __restrict__ h_fwd,
                                              const float* __restrict__ h_rev,
                                              float* __restrict__ out_fwd,
                                              float* __restrict__ out_rev) {
    int tid = blockIdx.x * blockDim.x + threadIdx.x;  // < 25.6M, fits int
    int e = tid >> 5;
    int f = tid & 31;
    if (e >= N_EDGES) return;
    int r = ei[e];
    int c = ei[N_EDGES + e];
    float vf = inv_o[r] * h_fwd[r * F_IN + f];
    float vr = inv_i[c] * h_rev[c * F_IN + f];
    unsafeAtomicAdd(out_fwd + c * F_IN + f, vf);
    unsafeAtomicAdd(out_rev + r * F_IN + f, vr);
}

// ---------------------------------------------------------------------------
// Assemble effective 160x64 weights for the z and h gates.
// Input weight layout (2, K=3, C=96, 64); only rows 0..31 of C matter (H0=0).
// seg 0: w[0,0]+w[1,0] | seg1: w[0,1] | seg2: w[1,1] | seg3: w[0,2] | seg4: w[1,2]
// ---------------------------------------------------------------------------
__global__ __launch_bounds__(256) void k_prep(const float* __restrict__ wz,
                                              const float* __restrict__ wh,
                                              float* __restrict__ Wz,
                                              float* __restrict__ Wh) {
    int tid = blockIdx.x * blockDim.x + threadIdx.x;
    const int MAT = C_FEAT * F_OUT;  // 10240
    if (tid >= 2 * MAT) return;
    const float* src = (tid < MAT) ? wz : wh;
    float*       dst = (tid < MAT) ? Wz : Wh;
    int i = tid % MAT;
    int c = i / F_OUT;
    int o = i % F_OUT;
    int seg = c >> 5;
    int cc  = c & 31;
    // flat index for (d,k,cc,o): ((d*3+k)*96 + cc)*64 + o
    float val;
    if (seg == 0)      val = src[(0 * 96 + cc) * 64 + o] + src[(3 * 96 + cc) * 64 + o];
    else if (seg == 1) val = src[(1 * 96 + cc) * 64 + o];
    else if (seg == 2) val = src[(4 * 96 + cc) * 64 + o];
    else if (seg == 3) val = src[(2 * 96 + cc) * 64 + o];
    else               val = src[(5 * 96 + cc) * 64 + o];
    dst[i] = val;
}

// ---------------------------------------------------------------------------
// Fused: per-node feature assembly -> dual GEMV (z,h gates) -> sigmoid/tanh ->
// H = (1-z)*tanh -> relu -> 64x12 linear head.
// Block = 256 threads = 4 nodes x 64 output channels.
// ---------------------------------------------------------------------------
__global__ __launch_bounds__(256) void k_final(const float* __restrict__ X,
                                               const float* __restrict__ Tx1o,
                                               const float* __restrict__ Tx1i,
                                               const float* __restrict__ P2o,
                                               const float* __restrict__ P2i,
                                               const float* __restrict__ Wz,
                                               const float* __restrict__ Wh,
                                               const float* __restrict__ bz,
                                               const float* __restrict__ bh,
                                               const float* __restrict__ wlin,
                                               const float* __restrict__ blin,
                                               float* __restrict__ out) {
    __shared__ float f_lds[4][C_FEAT];
    __shared__ float r_lds[4][F_OUT];
    int tid   = threadIdx.x;
    int node0 = blockIdx.x * 4;

    // Cooperative feature staging: 4 nodes x 160 channels
    for (int i = tid; i < 4 * C_FEAT; i += 256) {
        int nl = i / C_FEAT;
        int c  = i % C_FEAT;
        int v  = node0 + nl;
        float val = 0.0f;
        if (v < N_NODES) {
            int seg = c >> 5;
            int cc  = c & 31;
            int idx = v * F_IN + cc;
            if (seg == 0)      val = X[idx];
            else if (seg == 1) val = Tx1o[idx];
            else if (seg == 2) val = Tx1i[idx];
            else if (seg == 3) val = 2.0f * P2o[idx] - X[idx];
            else               val = 2.0f * P2i[idx] - X[idx];
        }
        f_lds[nl][c] = val;
    }
    __syncthreads();

    int nl = tid >> 6;   // node within block (one wave per node)
    int o  = tid & 63;   // output channel
    float accz = bz[o];
    float acch = bh[o];
#pragma unroll 8
    for (int c = 0; c < C_FEAT; ++c) {
        float fv = f_lds[nl][c];             // LDS broadcast within wave
        accz = fmaf(fv, Wz[c * F_OUT + o], accz);  // coalesced 256B per wave
        acch = fmaf(fv, Wh[c * F_OUT + o], acch);
    }
    float z  = 1.0f / (1.0f + expf(-accz));
    float ht = tanhf(acch);
    float h  = (1.0f - z) * ht;
    r_lds[nl][o] = fmaxf(h, 0.0f);
    __syncthreads();

    // Linear head: 4 nodes x 12 periods = 48 active threads
    if (tid < 4 * PERIODS) {
        int nl2 = tid / PERIODS;
        int p   = tid % PERIODS;
        int v2  = node0 + nl2;
        if (v2 < N_NODES) {
            float acc = blin[p];
#pragma unroll
            for (int oo = 0; oo < F_OUT; ++oo)
                acc = fmaf(r_lds[nl2][oo], wlin[oo * PERIODS + p], acc);
            out[v2 * PERIODS + p] = acc;
        }
    }
}

// ---------------------------------------------------------------------------
extern "C" void kernel_launch(void* const* d_in, const int* in_sizes, int n_in,
                              void* d_out, int out_size, void* d_ws, size_t ws_size,
                              hipStream_t stream) {
    const float* x    = (const float*)d_in[0];
    const int*   ei   = (const int*)d_in[1];
    const float* ew   = (const float*)d_in[2];
    const float* wz   = (const float*)d_in[3];
    const float* bz   = (const float*)d_in[4];
    // d_in[5], d_in[6] = w_r, b_r : provably unused (H0 == 0)
    const float* wh   = (const float*)d_in[7];
    const float* bh   = (const float*)d_in[8];
    const float* wlin = (const float*)d_in[9];
    const float* blin = (const float*)d_in[10];

    float* ws      = (float*)d_ws;
    float* deg_out = ws;
    float* deg_in  = deg_out + N_NODES;
    float* Tx1o    = deg_in + N_NODES;
    float* Tx1i    = Tx1o + (size_t)N_NODES * F_IN;
    float* P2o     = Tx1i + (size_t)N_NODES * F_IN;
    float* P2i     = P2o + (size_t)N_NODES * F_IN;
    float* Wz      = P2i + (size_t)N_NODES * F_IN;
    float* Wh      = Wz + C_FEAT * F_OUT;

    // zero all accumulators (ws is poisoned 0xAA once; we must re-zero every call)
    size_t zero_bytes = (size_t)(2 * N_NODES + 4 * (size_t)N_NODES * F_IN) * sizeof(float);
    hipMemsetAsync(ws, 0, zero_bytes, stream);

    k_prep<<<(2 * C_FEAT * F_OUT + 255) / 256, 256, 0, stream>>>(wz, wh, Wz, Wh);
    k_deg<<<(N_EDGES + 255) / 256, 256, 0, stream>>>(ei, ew, deg_out, deg_in);
    k_inv<<<(N_NODES + 255) / 256, 256, 0, stream>>>(deg_out, deg_in);

    // step 1: Tx1o = prop_fwd(X), Tx1i = prop_rev(X)
    k_prop<<<(N_EDGES * 32) / 256, 256, 0, stream>>>(ei, deg_out, deg_in, x, x, Tx1o, Tx1i);
    // step 2: P2o = prop_fwd(Tx1o), P2i = prop_rev(Tx1i)  (Tx2 = 2*P2 - X in k_final)
    k_prop<<<(N_EDGES * 32) / 256, 256, 0, stream>>>(ei, deg_out, deg_in, Tx1o, Tx1i, P2o, P2i);

    k_final<<<(N_NODES + 3) / 4, 256, 0, stream>>>(x, Tx1o, Tx1i, P2o, P2i, Wz, Wh,
                                                   bz, bh, wlin, blin, (float*)d_out);
}

// Round 2
// 548.132 us; speedup vs baseline: 1.0139x; 1.0139x over previous
//
#include <hip/hip_runtime.h>

#define N_NODES 50000
#define N_EDGES 800000
#define F_IN    32
#define F_OUT   64
#define PERIODS 12
#define C_FEAT  160   // [X, Tx1o, Tx1i, Tx2o, Tx2i] each 32 channels

#define SCAN_N  (2 * N_NODES)                       // 100000 combined counts
#define SCAN_BS 256
#define SCAN_NB ((SCAN_N + SCAN_BS - 1) / SCAN_BS)  // 391

// ---------------------------------------------------------------------------
// Weighted degrees + CSR histograms.
//   deg_out[row]+=w, deg_in[col]+=w (float), cnt[col]++ (fwd CSR, grouped by
//   dst=col), cnt[N+row]++ (rev CSR, grouped by dst=row).
// ---------------------------------------------------------------------------
__global__ __launch_bounds__(256) void k_deg(const int* __restrict__ ei,
                                             const float* __restrict__ ew,
                                             float* __restrict__ deg_out,
                                             float* __restrict__ deg_in,
                                             int* __restrict__ cnt) {
    int e = blockIdx.x * blockDim.x + threadIdx.x;
    if (e >= N_EDGES) return;
    int r = ei[e];
    int c = ei[N_EDGES + e];
    float w = ew[e];
    unsafeAtomicAdd(deg_out + r, w);
    unsafeAtomicAdd(deg_in + c, w);
    atomicAdd(cnt + c, 1);
    atomicAdd(cnt + N_NODES + r, 1);
}

__global__ __launch_bounds__(256) void k_inv(float* __restrict__ deg_out,
                                             float* __restrict__ deg_in) {
    int v = blockIdx.x * blockDim.x + threadIdx.x;
    if (v >= N_NODES) return;
    deg_out[v] = 1.0f / deg_out[v];
    deg_in[v]  = 1.0f / deg_in[v];
}

// ---------------------------------------------------------------------------
// Exclusive scan of cnt[SCAN_N] -> off[SCAN_N] (3 kernels)
// ---------------------------------------------------------------------------
__global__ __launch_bounds__(SCAN_BS) void k_scan1(const int* __restrict__ cnt,
                                                   int* __restrict__ off,
                                                   int* __restrict__ bsum) {
    __shared__ int lds[SCAN_BS];
    int g = blockIdx.x * SCAN_BS + threadIdx.x;
    int v = (g < SCAN_N) ? cnt[g] : 0;
    int orig = v;
    lds[threadIdx.x] = v;
    __syncthreads();
    for (int d = 1; d < SCAN_BS; d <<= 1) {
        int t = (threadIdx.x >= d) ? lds[threadIdx.x - d] : 0;
        __syncthreads();
        lds[threadIdx.x] += t;
        __syncthreads();
    }
    if (g < SCAN_N) off[g] = lds[threadIdx.x] - orig;   // exclusive
    if (threadIdx.x == SCAN_BS - 1) bsum[blockIdx.x] = lds[threadIdx.x];
}

__global__ __launch_bounds__(512) void k_scan2(int* __restrict__ bsum) {
    __shared__ int lds[512];
    int t = threadIdx.x;
    int v = (t < SCAN_NB) ? bsum[t] : 0;
    int orig = v;
    lds[t] = v;
    __syncthreads();
    for (int d = 1; d < 512; d <<= 1) {
        int x = (t >= d) ? lds[t - d] : 0;
        __syncthreads();
        lds[t] += x;
        __syncthreads();
    }
    if (t < SCAN_NB) bsum[t] = lds[t] - orig;           // exclusive
}

__global__ __launch_bounds__(SCAN_BS) void k_scan3(int* __restrict__ off,
                                                   const int* __restrict__ bsum) {
    int g = blockIdx.x * SCAN_BS + threadIdx.x;
    if (g < SCAN_N) off[g] += bsum[blockIdx.x];
}

// ---------------------------------------------------------------------------
// Counting-sort scatter: place (neighbor, coef) pairs. Consumes off[] by
// atomicAdd; afterwards off[i] == start[i+1] (combined CSR is contiguous),
// so gather reads beg = (i ? off[i-1] : 0), end = off[i].
//   fwd list of dst=col holds (row, inv_o[row]);  message = inv_o[src]*h[src]
//   rev list of dst=row holds (col, inv_i[col])
// ---------------------------------------------------------------------------
__global__ __launch_bounds__(256) void k_scatter(const int* __restrict__ ei,
                                                 const float* __restrict__ inv_o,
                                                 const float* __restrict__ inv_i,
                                                 int* __restrict__ off,
                                                 int2* __restrict__ csr) {
    int e = blockIdx.x * blockDim.x + threadIdx.x;
    if (e >= N_EDGES) return;
    int r = ei[e];
    int c = ei[N_EDGES + e];
    int p1 = atomicAdd(off + c, 1);
    csr[p1] = make_int2(r, __float_as_int(inv_o[r]));
    int p2 = atomicAdd(off + N_NODES + r, 1);
    csr[p2] = make_int2(c, __float_as_int(inv_i[c]));
}

// ---------------------------------------------------------------------------
// Gather propagation, no atomics. idx in [0, 2N): first N = fwd, rest = rev.
// 32 lanes per (node,dir): pair load broadcasts, feature load = one 128B line.
// ---------------------------------------------------------------------------
__global__ __launch_bounds__(256) void k_gather(const int* __restrict__ off,
                                                const int2* __restrict__ csr,
                                                const float* __restrict__ h_fwd,
                                                const float* __restrict__ h_rev,
                                                float* __restrict__ out_fwd,
                                                float* __restrict__ out_rev) {
    int tid = blockIdx.x * blockDim.x + threadIdx.x;
    int idx = tid >> 5;
    int f   = tid & 31;
    if (idx >= SCAN_N) return;
    bool fwd = idx < N_NODES;
    const float* h = fwd ? h_fwd : h_rev;
    int beg = (idx == 0) ? 0 : off[idx - 1];
    int end = off[idx];
    float acc = 0.0f;
    int j = beg;
    if (j < end) {
        int2 pr = csr[j];
        for (++j; j < end; ++j) {
            int2 nx = csr[j];                        // prefetch next pair
            acc = fmaf(__int_as_float(pr.y), h[pr.x * F_IN + f], acc);
            pr = nx;
        }
        acc = fmaf(__int_as_float(pr.y), h[pr.x * F_IN + f], acc);
    }
    int v = fwd ? idx : idx - N_NODES;
    (fwd ? out_fwd : out_rev)[v * F_IN + f] = acc;
}

// ---------------------------------------------------------------------------
// Assemble effective 160x64 weights (H0==0 kills rows 32..95 of each slice).
// ---------------------------------------------------------------------------
__global__ __launch_bounds__(256) void k_prep(const float* __restrict__ wz,
                                              const float* __restrict__ wh,
                                              float* __restrict__ Wz,
                                              float* __restrict__ Wh) {
    int tid = blockIdx.x * blockDim.x + threadIdx.x;
    const int MAT = C_FEAT * F_OUT;  // 10240
    if (tid >= 2 * MAT) return;
    const float* src = (tid < MAT) ? wz : wh;
    float*       dst = (tid < MAT) ? Wz : Wh;
    int i = tid % MAT;
    int c = i / F_OUT;
    int o = i % F_OUT;
    int seg = c >> 5;
    int cc  = c & 31;
    float val;
    if (seg == 0)      val = src[(0 * 96 + cc) * 64 + o] + src[(3 * 96 + cc) * 64 + o];
    else if (seg == 1) val = src[(1 * 96 + cc) * 64 + o];
    else if (seg == 2) val = src[(4 * 96 + cc) * 64 + o];
    else if (seg == 3) val = src[(2 * 96 + cc) * 64 + o];
    else               val = src[(5 * 96 + cc) * 64 + o];
    dst[i] = val;
}

// ---------------------------------------------------------------------------
// Fused epilogue: feature assembly -> dual GEMV -> sigmoid/tanh ->
// H=(1-z)*tanh -> relu -> 64x12 head.  Block = 4 nodes x 64 channels.
// ---------------------------------------------------------------------------
__global__ __launch_bounds__(256) void k_final(const float* __restrict__ X,
                                               const float* __restrict__ Tx1o,
                                               const float* __restrict__ Tx1i,
                                               const float* __restrict__ P2o,
                                               const float* __restrict__ P2i,
                                               const float* __restrict__ Wz,
                                               const float* __restrict__ Wh,
                                               const float* __restrict__ bz,
                                               const float* __restrict__ bh,
                                               const float* __restrict__ wlin,
                                               const float* __restrict__ blin,
                                               float* __restrict__ out) {
    __shared__ float f_lds[4][C_FEAT];
    __shared__ float r_lds[4][F_OUT];
    int tid   = threadIdx.x;
    int node0 = blockIdx.x * 4;

    for (int i = tid; i < 4 * C_FEAT; i += 256) {
        int nl = i / C_FEAT;
        int c  = i % C_FEAT;
        int v  = node0 + nl;
        float val = 0.0f;
        if (v < N_NODES) {
            int seg = c >> 5;
            int cc  = c & 31;
            int idx = v * F_IN + cc;
            if (seg == 0)      val = X[idx];
            else if (seg == 1) val = Tx1o[idx];
            else if (seg == 2) val = Tx1i[idx];
            else if (seg == 3) val = 2.0f * P2o[idx] - X[idx];
            else               val = 2.0f * P2i[idx] - X[idx];
        }
        f_lds[nl][c] = val;
    }
    __syncthreads();

    int nl = tid >> 6;
    int o  = tid & 63;
    float accz = bz[o];
    float acch = bh[o];
#pragma unroll 8
    for (int c = 0; c < C_FEAT; ++c) {
        float fv = f_lds[nl][c];
        accz = fmaf(fv, Wz[c * F_OUT + o], accz);
        acch = fmaf(fv, Wh[c * F_OUT + o], acch);
    }
    float z  = 1.0f / (1.0f + expf(-accz));
    float ht = tanhf(acch);
    float h  = (1.0f - z) * ht;
    r_lds[nl][o] = fmaxf(h, 0.0f);
    __syncthreads();

    if (tid < 4 * PERIODS) {
        int nl2 = tid / PERIODS;
        int p   = tid % PERIODS;
        int v2  = node0 + nl2;
        if (v2 < N_NODES) {
            float acc = blin[p];
#pragma unroll
            for (int oo = 0; oo < F_OUT; ++oo)
                acc = fmaf(r_lds[nl2][oo], wlin[oo * PERIODS + p], acc);
            out[v2 * PERIODS + p] = acc;
        }
    }
}

// ---------------------------------------------------------------------------
extern "C" void kernel_launch(void* const* d_in, const int* in_sizes, int n_in,
                              void* d_out, int out_size, void* d_ws, size_t ws_size,
                              hipStream_t stream) {
    const float* x    = (const float*)d_in[0];
    const int*   ei   = (const int*)d_in[1];
    const float* ew   = (const float*)d_in[2];
    const float* wz   = (const float*)d_in[3];
    const float* bz   = (const float*)d_in[4];
    // d_in[5], d_in[6] = w_r, b_r : provably unused (H0 == 0)
    const float* wh   = (const float*)d_in[7];
    const float* bh   = (const float*)d_in[8];
    const float* wlin = (const float*)d_in[9];
    const float* blin = (const float*)d_in[10];

    // workspace layout (all 4B elements; int2 region is 8B aligned:
    // (100000+100000+100000+512)*4 = 1202048 bytes, divisible by 8)
    float* deg_out = (float*)d_ws;                     // [N] zeroed
    float* deg_in  = deg_out + N_NODES;                // [N] zeroed
    int*   cnt     = (int*)(deg_in + N_NODES);         // [2N] zeroed
    int*   off     = cnt + SCAN_N;                     // [2N]
    int*   bsum    = off + SCAN_N;                     // [512]
    int2*  csr     = (int2*)(bsum + 512);              // [2E]
    float* Tx1o    = (float*)(csr + 2 * N_EDGES);      // [N*32]
    float* Tx1i    = Tx1o + (size_t)N_NODES * F_IN;
    float* P2o     = Tx1i + (size_t)N_NODES * F_IN;
    float* P2i     = P2o + (size_t)N_NODES * F_IN;
    float* Wz      = P2i + (size_t)N_NODES * F_IN;     // [160*64]
    float* Wh      = Wz + C_FEAT * F_OUT;

    // zero only deg + cnt (0.8 MB); everything else is write-before-read
    hipMemsetAsync(d_ws, 0, (size_t)(2 * N_NODES + SCAN_N) * sizeof(float), stream);

    k_prep<<<(2 * C_FEAT * F_OUT + 255) / 256, 256, 0, stream>>>(wz, wh, Wz, Wh);
    k_deg<<<(N_EDGES + 255) / 256, 256, 0, stream>>>(ei, ew, deg_out, deg_in, cnt);
    k_inv<<<(N_NODES + 255) / 256, 256, 0, stream>>>(deg_out, deg_in);

    k_scan1<<<SCAN_NB, SCAN_BS, 0, stream>>>(cnt, off, bsum);
    k_scan2<<<1, 512, 0, stream>>>(bsum);
    k_scan3<<<SCAN_NB, SCAN_BS, 0, stream>>>(off, bsum);

    k_scatter<<<(N_EDGES + 255) / 256, 256, 0, stream>>>(ei, deg_out, deg_in, off, csr);

    // step 1: Tx1o = prop_fwd(X), Tx1i = prop_rev(X)
    k_gather<<<(SCAN_N * 32) / 256, 256, 0, stream>>>(off, csr, x, x, Tx1o, Tx1i);
    // step 2: P2o = prop_fwd(Tx1o), P2i = prop_rev(Tx1i); Tx2 = 2*P2 - X in k_final
    k_gather<<<(SCAN_N * 32) / 256, 256, 0, stream>>>(off, csr, Tx1o, Tx1i, P2o, P2i);

    k_final<<<(N_NODES + 3) / 4, 256, 0, stream>>>(x, Tx1o, Tx1i, P2o, P2i, Wz, Wh,
                                                   bz, bh, wlin, blin, (float*)d_out);
}

// Round 3
// 492.427 us; speedup vs baseline: 1.1286x; 1.1131x over previous
//
#include <hip/hip_runtime.h>

#define N_NODES 50000
#define N_EDGES 800000
#define F_IN    32
#define F_OUT   64
#define PERIODS 12
#define C_FEAT  160   // [X, Tx1o, Tx1i, Tx2o, Tx2i] each 32 channels
#define W_LD    192   // padded row stride (XOR-swizzle closure of 160)

#define SCAN_N  (2 * N_NODES)                       // 100000 combined counts
#define SCAN_BS 256
#define SCAN_NB ((SCAN_N + SCAN_BS - 1) / SCAN_BS)  // 391

typedef __attribute__((ext_vector_type(8))) short s16x8;
typedef __attribute__((ext_vector_type(4))) float f32x4;

static __device__ __forceinline__ ushort f2bf(float f) {
    unsigned u = __float_as_uint(f);
    unsigned r = (u + 0x7FFFu + ((u >> 16) & 1u)) >> 16;   // RNE
    return (ushort)r;
}

// ---------------------------------------------------------------------------
// Weighted degrees + CSR histograms.
// ---------------------------------------------------------------------------
__global__ __launch_bounds__(256) void k_deg(const int* __restrict__ ei,
                                             const float* __restrict__ ew,
                                             float* __restrict__ deg_out,
                                             float* __restrict__ deg_in,
                                             int* __restrict__ cnt) {
    int e = blockIdx.x * blockDim.x + threadIdx.x;
    if (e >= N_EDGES) return;
    int r = ei[e];
    int c = ei[N_EDGES + e];
    float w = ew[e];
    unsafeAtomicAdd(deg_out + r, w);
    unsafeAtomicAdd(deg_in + c, w);
    atomicAdd(cnt + c, 1);
    atomicAdd(cnt + N_NODES + r, 1);
}

__global__ __launch_bounds__(256) void k_inv(float* __restrict__ deg_out,
                                             float* __restrict__ deg_in) {
    int v = blockIdx.x * blockDim.x + threadIdx.x;
    if (v >= N_NODES) return;
    deg_out[v] = 1.0f / deg_out[v];
    deg_in[v]  = 1.0f / deg_in[v];
}

// ---------------------------------------------------------------------------
// Exclusive scan of cnt[SCAN_N] -> off[SCAN_N]
// ---------------------------------------------------------------------------
__global__ __launch_bounds__(SCAN_BS) void k_scan1(const int* __restrict__ cnt,
                                                   int* __restrict__ off,
                                                   int* __restrict__ bsum) {
    __shared__ int lds[SCAN_BS];
    int g = blockIdx.x * SCAN_BS + threadIdx.x;
    int v = (g < SCAN_N) ? cnt[g] : 0;
    int orig = v;
    lds[threadIdx.x] = v;
    __syncthreads();
    for (int d = 1; d < SCAN_BS; d <<= 1) {
        int t = (threadIdx.x >= d) ? lds[threadIdx.x - d] : 0;
        __syncthreads();
        lds[threadIdx.x] += t;
        __syncthreads();
    }
    if (g < SCAN_N) off[g] = lds[threadIdx.x] - orig;   // exclusive
    if (threadIdx.x == SCAN_BS - 1) bsum[blockIdx.x] = lds[threadIdx.x];
}

__global__ __launch_bounds__(512) void k_scan2(int* __restrict__ bsum) {
    __shared__ int lds[512];
    int t = threadIdx.x;
    int v = (t < SCAN_NB) ? bsum[t] : 0;
    int orig = v;
    lds[t] = v;
    __syncthreads();
    for (int d = 1; d < 512; d <<= 1) {
        int x = (t >= d) ? lds[t - d] : 0;
        __syncthreads();
        lds[t] += x;
        __syncthreads();
    }
    if (t < SCAN_NB) bsum[t] = lds[t] - orig;           // exclusive
}

__global__ __launch_bounds__(SCAN_BS) void k_scan3(int* __restrict__ off,
                                                   const int* __restrict__ bsum) {
    int g = blockIdx.x * SCAN_BS + threadIdx.x;
    if (g < SCAN_N) off[g] += bsum[blockIdx.x];
}

// ---------------------------------------------------------------------------
// Counting-sort scatter: place (neighbor, coef) pairs.
// ---------------------------------------------------------------------------
__global__ __launch_bounds__(256) void k_scatter(const int* __restrict__ ei,
                                                 const float* __restrict__ inv_o,
                                                 const float* __restrict__ inv_i,
                                                 int* __restrict__ off,
                                                 int2* __restrict__ csr) {
    int e = blockIdx.x * blockDim.x + threadIdx.x;
    if (e >= N_EDGES) return;
    int r = ei[e];
    int c = ei[N_EDGES + e];
    int p1 = atomicAdd(off + c, 1);
    csr[p1] = make_int2(r, __float_as_int(inv_o[r]));
    int p2 = atomicAdd(off + N_NODES + r, 1);
    csr[p2] = make_int2(c, __float_as_int(inv_i[c]));
}

// ---------------------------------------------------------------------------
// Gather propagation, no atomics. idx in [0, 2N): first N = fwd, rest = rev.
// ---------------------------------------------------------------------------
__global__ __launch_bounds__(256) void k_gather(const int* __restrict__ off,
                                                const int2* __restrict__ csr,
                                                const float* __restrict__ h_fwd,
                                                const float* __restrict__ h_rev,
                                                float* __restrict__ out_fwd,
                                                float* __restrict__ out_rev) {
    int tid = blockIdx.x * blockDim.x + threadIdx.x;
    int idx = tid >> 5;
    int f   = tid & 31;
    if (idx >= SCAN_N) return;
    bool fwd = idx < N_NODES;
    const float* h = fwd ? h_fwd : h_rev;
    int beg = (idx == 0) ? 0 : off[idx - 1];
    int end = off[idx];
    float acc = 0.0f;
    int j = beg;
    if (j < end) {
        int2 pr = csr[j];
        for (++j; j < end; ++j) {
            int2 nx = csr[j];                        // prefetch next pair
            acc = fmaf(__int_as_float(pr.y), h[pr.x * F_IN + f], acc);
            pr = nx;
        }
        acc = fmaf(__int_as_float(pr.y), h[pr.x * F_IN + f], acc);
    }
    int v = fwd ? idx : idx - N_NODES;
    (fwd ? out_fwd : out_rev)[v * F_IN + f] = acc;
}

// ---------------------------------------------------------------------------
// Build bf16 transposed+swizzled weight Wt[o][s], o in [0,128): z cols then h.
// Storage slot s holds element e = s ^ ((o&7)<<3); e>=160 -> 0.
// Source layout (2,3,96,64); rows 32..95 dead (H0==0).
// ---------------------------------------------------------------------------
__global__ __launch_bounds__(256) void k_prep(const float* __restrict__ wz,
                                              const float* __restrict__ wh,
                                              ushort* __restrict__ Wt) {
    int tid = blockIdx.x * blockDim.x + threadIdx.x;
    if (tid >= 128 * W_LD) return;
    int o = tid / W_LD;
    int s = tid % W_LD;
    int e = s ^ ((o & 7) << 3);
    float val = 0.0f;
    if (e < C_FEAT) {
        int seg = e >> 5;
        int cc  = e & 31;
        const float* src = (o < 64) ? wz : wh;
        int oo = o & 63;
        if (seg == 0)      val = src[(0 * 96 + cc) * 64 + oo] + src[(3 * 96 + cc) * 64 + oo];
        else if (seg == 1) val = src[(1 * 96 + cc) * 64 + oo];
        else if (seg == 2) val = src[(4 * 96 + cc) * 64 + oo];
        else if (seg == 3) val = src[(2 * 96 + cc) * 64 + oo];
        else               val = src[(5 * 96 + cc) * 64 + oo];
    }
    Wt[tid] = f2bf(val);
}

// ---------------------------------------------------------------------------
// MFMA epilogue GEMM: [32 nodes x 160] x [160 x 128] per block, bf16 in /
// fp32 acc, then sigmoid/tanh gating + relu + 64x12 head.
// 256 threads = 4 waves; wave w: row-tile (w&1), col-tiles 4*(w>>1)+0..3.
// ---------------------------------------------------------------------------
__global__ __launch_bounds__(256) void k_final(const float* __restrict__ X,
                                               const float* __restrict__ Tx1o,
                                               const float* __restrict__ Tx1i,
                                               const float* __restrict__ P2o,
                                               const float* __restrict__ P2i,
                                               const ushort* __restrict__ Wt,
                                               const float* __restrict__ bz,
                                               const float* __restrict__ bh,
                                               const float* __restrict__ wlin,
                                               const float* __restrict__ blin,
                                               float* __restrict__ out) {
    __shared__ __align__(16) ushort fA[32][W_LD];      // 12288 B (bf16, swizzled)
    __shared__ __align__(16) ushort fW[128 * W_LD];    // 49152 B (bf16, swizzled)
    __shared__ float g[32][132];                       // 16896 B (pad 132 vs 128)
    int tid   = threadIdx.x;
    int node0 = blockIdx.x * 32;

    // stage weights linearly (swizzle pre-applied in global Wt)
    {
        const uint4* src = (const uint4*)Wt;
        uint4*       dst = (uint4*)fW;
        for (int i = tid; i < (128 * W_LD) / 8; i += 256) dst[i] = src[i];
    }
    // stage features bf16, swizzled: slot s of row r holds element s^((r&7)<<3)
    for (int i = tid; i < 32 * W_LD; i += 256) {
        int r = i / W_LD;
        int s = i % W_LD;
        int e = s ^ ((r & 7) << 3);
        int v = node0 + r;
        float val = 0.0f;
        if (e < C_FEAT && v < N_NODES) {
            int seg = e >> 5;
            int cc  = e & 31;
            int idx = v * F_IN + cc;
            if (seg == 0)      val = X[idx];
            else if (seg == 1) val = Tx1o[idx];
            else if (seg == 2) val = Tx1i[idx];
            else if (seg == 3) val = 2.0f * P2o[idx] - X[idx];
            else               val = 2.0f * P2i[idx] - X[idx];
        }
        fA[r][s] = f2bf(val);
    }
    __syncthreads();

    int w  = tid >> 6;
    int l  = tid & 63;
    int rt = w & 1;            // row tile (16 nodes)
    int c0 = (w >> 1) * 64;    // col base
    int lr = l & 15;
    int lg = l >> 4;

    // A fragments: row = rt*16+lr, k = kb*32 + lg*8 + j
    s16x8 a[5];
    {
        int row = rt * 16 + lr;
        int sw  = (row & 7) << 3;
#pragma unroll
        for (int kb = 0; kb < 5; ++kb) {
            int k0 = kb * 32 + lg * 8;
            a[kb] = *(const s16x8*)&fA[row][k0 ^ sw];
        }
    }
    f32x4 acc[4] = {};
#pragma unroll
    for (int ct = 0; ct < 4; ++ct) {
        int col = c0 + ct * 16 + lr;
        int sw  = (col & 7) << 3;
#pragma unroll
        for (int kb = 0; kb < 5; ++kb) {
            int k0 = kb * 32 + lg * 8;
            s16x8 b = *(const s16x8*)&fW[col * W_LD + (k0 ^ sw)];
            acc[ct] = __builtin_amdgcn_mfma_f32_16x16x32_bf16(a[kb], b, acc[ct], 0, 0, 0);
        }
    }
    // D mapping: col = lane&15, row = (lane>>4)*4 + q  (verified m89/m91)
#pragma unroll
    for (int ct = 0; ct < 4; ++ct)
#pragma unroll
        for (int q = 0; q < 4; ++q)
            g[rt * 16 + lg * 4 + q][c0 + ct * 16 + lr] = acc[ct][q];
    __syncthreads();

    // activation: z = cols 0..63, h = cols 64..127; r_lds overlays fA
    float* r_lds = (float*)&fA[0][0];   // 32*64 floats = 8 KB <= 12 KB
    for (int i = tid; i < 32 * 64; i += 256) {
        int n = i >> 6;
        int o = i & 63;
        float zp = g[n][o] + bz[o];
        float hp = g[n][64 + o] + bh[o];
        float z  = 1.0f / (1.0f + __expf(-zp));
        float ht = tanhf(hp);
        r_lds[i] = fmaxf((1.0f - z) * ht, 0.0f);
    }
    __syncthreads();

    for (int i = tid; i < 32 * PERIODS; i += 256) {
        int n = i / PERIODS;
        int p = i % PERIODS;
        int v = node0 + n;
        if (v < N_NODES) {
            float acc2 = blin[p];
#pragma unroll
            for (int oo = 0; oo < F_OUT; ++oo)
                acc2 = fmaf(r_lds[n * 64 + oo], wlin[oo * PERIODS + p], acc2);
            out[v * PERIODS + p] = acc2;
        }
    }
}

// ---------------------------------------------------------------------------
extern "C" void kernel_launch(void* const* d_in, const int* in_sizes, int n_in,
                              void* d_out, int out_size, void* d_ws, size_t ws_size,
                              hipStream_t stream) {
    const float* x    = (const float*)d_in[0];
    const int*   ei   = (const int*)d_in[1];
    const float* ew   = (const float*)d_in[2];
    const float* wz   = (const float*)d_in[3];
    const float* bz   = (const float*)d_in[4];
    // d_in[5], d_in[6] = w_r, b_r : provably unused (H0 == 0)
    const float* wh   = (const float*)d_in[7];
    const float* bh   = (const float*)d_in[8];
    const float* wlin = (const float*)d_in[9];
    const float* blin = (const float*)d_in[10];

    // workspace layout
    float*  deg_out = (float*)d_ws;                    // [N] zeroed
    float*  deg_in  = deg_out + N_NODES;               // [N] zeroed
    int*    cnt     = (int*)(deg_in + N_NODES);        // [2N] zeroed
    int*    off     = cnt + SCAN_N;                    // [2N]
    int*    bsum    = off + SCAN_N;                    // [512]
    int2*   csr     = (int2*)(bsum + 512);             // [2E] (8B aligned)
    float*  Tx1o    = (float*)(csr + 2 * N_EDGES);     // [N*32]
    float*  Tx1i    = Tx1o + (size_t)N_NODES * F_IN;
    float*  P2o     = Tx1i + (size_t)N_NODES * F_IN;
    float*  P2i     = P2o + (size_t)N_NODES * F_IN;
    ushort* Wt      = (ushort*)(P2i + (size_t)N_NODES * F_IN);  // [128*192] bf16, 16B-aligned

    hipMemsetAsync(d_ws, 0, (size_t)(2 * N_NODES + SCAN_N) * sizeof(float), stream);

    k_prep<<<(128 * W_LD + 255) / 256, 256, 0, stream>>>(wz, wh, Wt);
    k_deg<<<(N_EDGES + 255) / 256, 256, 0, stream>>>(ei, ew, deg_out, deg_in, cnt);
    k_inv<<<(N_NODES + 255) / 256, 256, 0, stream>>>(deg_out, deg_in);

    k_scan1<<<SCAN_NB, SCAN_BS, 0, stream>>>(cnt, off, bsum);
    k_scan2<<<1, 512, 0, stream>>>(bsum);
    k_scan3<<<SCAN_NB, SCAN_BS, 0, stream>>>(off, bsum);

    k_scatter<<<(N_EDGES + 255) / 256, 256, 0, stream>>>(ei, deg_out, deg_in, off, csr);

    k_gather<<<(SCAN_N * 32) / 256, 256, 0, stream>>>(off, csr, x, x, Tx1o, Tx1i);
    k_gather<<<(SCAN_N * 32) / 256, 256, 0, stream>>>(off, csr, Tx1o, Tx1i, P2o, P2i);

    k_final<<<(N_NODES + 31) / 32, 256, 0, stream>>>(x, Tx1o, Tx1i, P2o, P2i, Wt,
                                                     bz, bh, wlin, blin, (float*)d_out);
}

// Round 4
// 247.755 us; speedup vs baseline: 2.2431x; 1.9876x over previous
//
#include <hip/hip_runtime.h>

#define N_NODES 50000
#define N_EDGES 800000
#define F_IN    32
#define F_OUT   64
#define PERIODS 12
#define C_FEAT  160   // [X, Tx1o, Tx1i, Tx2o, Tx2i] each 32 channels
#define W_LD    192   // padded row stride (XOR-swizzle closure of 160)

#define NKEY    (2 * N_NODES)    // 100000 combined keys: fwd=col, rev=N+row
#define NBIN    782              // ceil(100000/128) — 128 keys per bin
#define NBLK_A  128
#define EPB     (N_EDGES / NBLK_A)   // 6250 edges per A-block (exact)
#define TOT     (2 * N_EDGES)        // 1.6M CSR entries
#define SCANA_N (NBIN * NBLK_A)      // 100096 = 391*256 exactly
#define SCANA_NB 391

typedef __attribute__((ext_vector_type(8))) short s16x8;
typedef __attribute__((ext_vector_type(4))) float f32x4;

static __device__ __forceinline__ ushort f2bf(float f) {
    unsigned u = __float_as_uint(f);
    unsigned r = (u + 0x7FFFu + ((u >> 16) & 1u)) >> 16;   // RNE
    return (ushort)r;
}

// ---------------------------------------------------------------------------
// Pass A1: per-block LDS histogram of combined keys into 782 coarse bins.
// ---------------------------------------------------------------------------
__global__ __launch_bounds__(256) void k_histA(const int* __restrict__ ei,
                                               int* __restrict__ hist) {
    __shared__ int h[NBIN];
    int tid = threadIdx.x, blk = blockIdx.x;
    for (int i = tid; i < NBIN; i += 256) h[i] = 0;
    __syncthreads();
    int e0 = blk * EPB;
    for (int i = tid; i < EPB; i += 256) {
        int e = e0 + i;
        int r = ei[e];
        int c = ei[N_EDGES + e];
        atomicAdd(&h[c >> 7], 1);
        atomicAdd(&h[(N_NODES + r) >> 7], 1);
    }
    __syncthreads();
    for (int i = tid; i < NBIN; i += 256) hist[i * NBLK_A + blk] = h[i];
}

// ---------------------------------------------------------------------------
// Exclusive scan of hist[SCANA_N] -> scanA[SCANA_N]
// ---------------------------------------------------------------------------
__global__ __launch_bounds__(256) void k_scan1(const int* __restrict__ cnt,
                                               int* __restrict__ off,
                                               int* __restrict__ bsum) {
    __shared__ int lds[256];
    int g = blockIdx.x * 256 + threadIdx.x;
    int v = (g < SCANA_N) ? cnt[g] : 0;
    int orig = v;
    lds[threadIdx.x] = v;
    __syncthreads();
    for (int d = 1; d < 256; d <<= 1) {
        int t = (threadIdx.x >= d) ? lds[threadIdx.x - d] : 0;
        __syncthreads();
        lds[threadIdx.x] += t;
        __syncthreads();
    }
    if (g < SCANA_N) off[g] = lds[threadIdx.x] - orig;   // exclusive
    if (threadIdx.x == 255) bsum[blockIdx.x] = lds[threadIdx.x];
}

__global__ __launch_bounds__(512) void k_scan2(int* __restrict__ bsum) {
    __shared__ int lds[512];
    int t = threadIdx.x;
    int v = (t < SCANA_NB) ? bsum[t] : 0;
    int orig = v;
    lds[t] = v;
    __syncthreads();
    for (int d = 1; d < 512; d <<= 1) {
        int x = (t >= d) ? lds[t - d] : 0;
        __syncthreads();
        lds[t] += x;
        __syncthreads();
    }
    if (t < SCANA_NB) bsum[t] = lds[t] - orig;           // exclusive
}

__global__ __launch_bounds__(256) void k_scan3(int* __restrict__ off,
                                               const int* __restrict__ bsum) {
    int g = blockIdx.x * 256 + threadIdx.x;
    if (g < SCANA_N) off[g] += bsum[blockIdx.x];
}

// ---------------------------------------------------------------------------
// Pass A3: multi-split — place 8B items (key_low7 | src<<7, w) into bins.
// LDS cursors only; no global atomics.
// ---------------------------------------------------------------------------
__global__ __launch_bounds__(256) void k_binA(const int* __restrict__ ei,
                                              const float* __restrict__ ew,
                                              const int* __restrict__ scanA,
                                              uint2* __restrict__ binned) {
    __shared__ int cur[NBIN];
    int tid = threadIdx.x, blk = blockIdx.x;
    for (int i = tid; i < NBIN; i += 256) cur[i] = scanA[i * NBLK_A + blk];
    __syncthreads();
    int e0 = blk * EPB;
    for (int i = tid; i < EPB; i += 256) {
        int e = e0 + i;
        int r = ei[e];
        int c = ei[N_EDGES + e];
        unsigned wb = __float_as_uint(ew[e]);
        int k1 = c;               // fwd: grouped by col, src = row
        int k2 = N_NODES + r;     // rev: grouped by row, src = col
        int p1 = atomicAdd(&cur[k1 >> 7], 1);
        binned[p1] = make_uint2((unsigned)((k1 & 127) | (r << 7)), wb);
        int p2 = atomicAdd(&cur[k2 >> 7], 1);
        binned[p2] = make_uint2((unsigned)((k2 & 127) | (c << 7)), wb);
    }
}

// ---------------------------------------------------------------------------
// Pass B: per-bin counting sort (one block per bin, 128 keys/bin).
// Also computes weighted-degree segment sums -> inv[key] = 1/deg, and off[key].
// ---------------------------------------------------------------------------
__global__ __launch_bounds__(256) void k_sortbin(const uint2* __restrict__ binned,
                                                 const int* __restrict__ scanA,
                                                 int* __restrict__ csr,
                                                 int* __restrict__ off,
                                                 float* __restrict__ inv) {
    __shared__ int cnt[128];
    __shared__ int sc[128];
    __shared__ int cur[128];
    __shared__ float deg[128];
    int tid = threadIdx.x;
    int b   = blockIdx.x;
    int base = scanA[b * NBLK_A];
    int end  = (b + 1 < NBIN) ? scanA[(b + 1) * NBLK_A] : TOT;
    if (tid < 128) { cnt[tid] = 0; deg[tid] = 0.0f; }
    __syncthreads();
    for (int i = base + tid; i < end; i += 256) {
        uint2 it = binned[i];
        int kl = it.x & 127;
        atomicAdd(&cnt[kl], 1);
        atomicAdd(&deg[kl], __uint_as_float(it.y));
    }
    __syncthreads();
    if (tid < 128) sc[tid] = cnt[tid];
    __syncthreads();
    for (int d = 1; d < 128; d <<= 1) {
        int t = (tid >= d && tid < 128) ? sc[tid - d] : 0;
        __syncthreads();
        if (tid < 128) sc[tid] += t;
        __syncthreads();
    }
    if (tid < 128) cur[tid] = sc[tid] - cnt[tid];   // exclusive
    __syncthreads();
    for (int i = base + tid; i < end; i += 256) {
        uint2 it = binned[i];
        int kl = it.x & 127;
        int pos = atomicAdd(&cur[kl], 1);
        csr[base + pos] = (int)(it.x >> 7);
    }
    if (tid < 128) {
        int key = (b << 7) + tid;                    // up to 100095; arrays padded
        off[key] = base + sc[tid] - cnt[tid];
        inv[key] = 1.0f / deg[tid];                  // inf for deg 0: never read
    }
    // off[100000] (gather sentinel) is auto-written by bin 781 = TOT.
}

// ---------------------------------------------------------------------------
// Gather propagation, no atomics. idx in [0, 2N): first N = fwd, rest = rev.
// coef: fwd entry src=r needs 1/deg_out[r] = inv[N+src]; rev: inv[src].
// ---------------------------------------------------------------------------
__global__ __launch_bounds__(256) void k_gather(const int* __restrict__ off,
                                                const int* __restrict__ csr,
                                                const float* __restrict__ inv,
                                                const float* __restrict__ h_fwd,
                                                const float* __restrict__ h_rev,
                                                float* __restrict__ out_fwd,
                                                float* __restrict__ out_rev) {
    int tid = blockIdx.x * blockDim.x + threadIdx.x;
    int idx = tid >> 5;
    int f   = tid & 31;
    if (idx >= NKEY) return;
    bool fwd = idx < N_NODES;
    const float* h    = fwd ? h_fwd : h_rev;
    const float* itab = inv + (fwd ? N_NODES : 0);
    int beg = off[idx];
    int end = off[idx + 1];
    float acc = 0.0f;
    int j = beg;
    if (j < end) {
        int s = csr[j];
        float cv = itab[s];
        for (++j; j < end; ++j) {
            int s2 = csr[j];                 // prefetch next (src, coef)
            float cv2 = itab[s2];
            acc = fmaf(cv, h[s * F_IN + f], acc);
            s = s2; cv = cv2;
        }
        acc = fmaf(cv, h[s * F_IN + f], acc);
    }
    int v = fwd ? idx : idx - N_NODES;
    (fwd ? out_fwd : out_rev)[v * F_IN + f] = acc;
}

// ---------------------------------------------------------------------------
// Build bf16 transposed+swizzled weight Wt[o][s], o in [0,128): z cols then h.
// Storage slot s holds element e = s ^ ((o&7)<<3); e>=160 -> 0.
// ---------------------------------------------------------------------------
__global__ __launch_bounds__(256) void k_prep(const float* __restrict__ wz,
                                              const float* __restrict__ wh,
                                              ushort* __restrict__ Wt) {
    int tid = blockIdx.x * blockDim.x + threadIdx.x;
    if (tid >= 128 * W_LD) return;
    int o = tid / W_LD;
    int s = tid % W_LD;
    int e = s ^ ((o & 7) << 3);
    float val = 0.0f;
    if (e < C_FEAT) {
        int seg = e >> 5;
        int cc  = e & 31;
        const float* src = (o < 64) ? wz : wh;
        int oo = o & 63;
        if (seg == 0)      val = src[(0 * 96 + cc) * 64 + oo] + src[(3 * 96 + cc) * 64 + oo];
        else if (seg == 1) val = src[(1 * 96 + cc) * 64 + oo];
        else if (seg == 2) val = src[(4 * 96 + cc) * 64 + oo];
        else if (seg == 3) val = src[(2 * 96 + cc) * 64 + oo];
        else               val = src[(5 * 96 + cc) * 64 + oo];
    }
    Wt[tid] = f2bf(val);
}

// ---------------------------------------------------------------------------
// MFMA epilogue GEMM: [32 nodes x 160] x [160 x 128] per block, bf16 in /
// fp32 acc, then sigmoid/tanh gating + relu + 64x12 head.
// ---------------------------------------------------------------------------
__global__ __launch_bounds__(256) void k_final(const float* __restrict__ X,
                                               const float* __restrict__ Tx1o,
                                               const float* __restrict__ Tx1i,
                                               const float* __restrict__ P2o,
                                               const float* __restrict__ P2i,
                                               const ushort* __restrict__ Wt,
                                               const float* __restrict__ bz,
                                               const float* __restrict__ bh,
                                               const float* __restrict__ wlin,
                                               const float* __restrict__ blin,
                                               float* __restrict__ out) {
    __shared__ __align__(16) ushort fA[32][W_LD];      // 12288 B (bf16, swizzled)
    __shared__ __align__(16) ushort fW[128 * W_LD];    // 49152 B (bf16, swizzled)
    __shared__ float g[32][132];                       // 16896 B
    int tid   = threadIdx.x;
    int node0 = blockIdx.x * 32;

    {
        const uint4* src = (const uint4*)Wt;
        uint4*       dst = (uint4*)fW;
        for (int i = tid; i < (128 * W_LD) / 8; i += 256) dst[i] = src[i];
    }
    for (int i = tid; i < 32 * W_LD; i += 256) {
        int r = i / W_LD;
        int s = i % W_LD;
        int e = s ^ ((r & 7) << 3);
        int v = node0 + r;
        float val = 0.0f;
        if (e < C_FEAT && v < N_NODES) {
            int seg = e >> 5;
            int cc  = e & 31;
            int idx = v * F_IN + cc;
            if (seg == 0)      val = X[idx];
            else if (seg == 1) val = Tx1o[idx];
            else if (seg == 2) val = Tx1i[idx];
            else if (seg == 3) val = 2.0f * P2o[idx] - X[idx];
            else               val = 2.0f * P2i[idx] - X[idx];
        }
        fA[r][s] = f2bf(val);
    }
    __syncthreads();

    int w  = tid >> 6;
    int l  = tid & 63;
    int rt = w & 1;
    int c0 = (w >> 1) * 64;
    int lr = l & 15;
    int lg = l >> 4;

    s16x8 a[5];
    {
        int row = rt * 16 + lr;
        int sw  = (row & 7) << 3;
#pragma unroll
        for (int kb = 0; kb < 5; ++kb) {
            int k0 = kb * 32 + lg * 8;
            a[kb] = *(const s16x8*)&fA[row][k0 ^ sw];
        }
    }
    f32x4 acc[4] = {};
#pragma unroll
    for (int ct = 0; ct < 4; ++ct) {
        int col = c0 + ct * 16 + lr;
        int sw  = (col & 7) << 3;
#pragma unroll
        for (int kb = 0; kb < 5; ++kb) {
            int k0 = kb * 32 + lg * 8;
            s16x8 b = *(const s16x8*)&fW[col * W_LD + (k0 ^ sw)];
            acc[ct] = __builtin_amdgcn_mfma_f32_16x16x32_bf16(a[kb], b, acc[ct], 0, 0, 0);
        }
    }
#pragma unroll
    for (int ct = 0; ct < 4; ++ct)
#pragma unroll
        for (int q = 0; q < 4; ++q)
            g[rt * 16 + lg * 4 + q][c0 + ct * 16 + lr] = acc[ct][q];
    __syncthreads();

    float* r_lds = (float*)&fA[0][0];   // 8 KB overlay
    for (int i = tid; i < 32 * 64; i += 256) {
        int n = i >> 6;
        int o = i & 63;
        float zp = g[n][o] + bz[o];
        float hp = g[n][64 + o] + bh[o];
        float z  = 1.0f / (1.0f + __expf(-zp));
        float ht = tanhf(hp);
        r_lds[i] = fmaxf((1.0f - z) * ht, 0.0f);
    }
    __syncthreads();

    for (int i = tid; i < 32 * PERIODS; i += 256) {
        int n = i / PERIODS;
        int p = i % PERIODS;
        int v = node0 + n;
        if (v < N_NODES) {
            float acc2 = blin[p];
#pragma unroll
            for (int oo = 0; oo < F_OUT; ++oo)
                acc2 = fmaf(r_lds[n * 64 + oo], wlin[oo * PERIODS + p], acc2);
            out[v * PERIODS + p] = acc2;
        }
    }
}

// ---------------------------------------------------------------------------
extern "C" void kernel_launch(void* const* d_in, const int* in_sizes, int n_in,
                              void* d_out, int out_size, void* d_ws, size_t ws_size,
                              hipStream_t stream) {
    const float* x    = (const float*)d_in[0];
    const int*   ei   = (const int*)d_in[1];
    const float* ew   = (const float*)d_in[2];
    const float* wz   = (const float*)d_in[3];
    const float* bz   = (const float*)d_in[4];
    // d_in[5], d_in[6] = w_r, b_r : provably unused (H0 == 0)
    const float* wh   = (const float*)d_in[7];
    const float* bh   = (const float*)d_in[8];
    const float* wlin = (const float*)d_in[9];
    const float* blin = (const float*)d_in[10];

    // workspace layout — everything is write-before-read; NO memset needed
    int*    histA  = (int*)d_ws;                       // [100096]
    int*    scanA  = histA + SCANA_N;                  // [100096]
    int*    bsum   = scanA + SCANA_N;                  // [512]
    uint2*  binned = (uint2*)(bsum + 512);             // [1.6M] (802816 B offset: 8B-aligned)
    int*    csr    = (int*)(binned + TOT);             // [1.6M]
    int*    off    = csr + TOT;                        // [100100] (writes to 100095, reads to 100000)
    float*  inv    = (float*)(off + 100100);           // [100096]
    float*  Tx1o   = inv + SCANA_N;                    // [N*32] x4
    float*  Tx1i   = Tx1o + (size_t)N_NODES * F_IN;
    float*  P2o    = Tx1i + (size_t)N_NODES * F_IN;
    float*  P2i    = P2o + (size_t)N_NODES * F_IN;
    ushort* Wt     = (ushort*)(P2i + (size_t)N_NODES * F_IN);  // [128*192] bf16

    k_prep<<<(128 * W_LD + 255) / 256, 256, 0, stream>>>(wz, wh, Wt);

    // CSR build: histogram -> scan -> multi-split -> per-bin counting sort
    k_histA<<<NBLK_A, 256, 0, stream>>>(ei, histA);
    k_scan1<<<SCANA_NB, 256, 0, stream>>>(histA, scanA, bsum);
    k_scan2<<<1, 512, 0, stream>>>(bsum);
    k_scan3<<<SCANA_NB, 256, 0, stream>>>(scanA, bsum);
    k_binA<<<NBLK_A, 256, 0, stream>>>(ei, ew, scanA, binned);
    k_sortbin<<<NBIN, 256, 0, stream>>>(binned, scanA, csr, off, inv);

    // step 1: Tx1o = prop_fwd(X), Tx1i = prop_rev(X)
    k_gather<<<(NKEY * 32) / 256, 256, 0, stream>>>(off, csr, inv, x, x, Tx1o, Tx1i);
    // step 2: P2o = prop_fwd(Tx1o), P2i = prop_rev(Tx1i); Tx2 = 2*P2 - X in k_final
    k_gather<<<(NKEY * 32) / 256, 256, 0, stream>>>(off, csr, inv, Tx1o, Tx1i, P2o, P2i);

    k_final<<<(N_NODES + 31) / 32, 256, 0, stream>>>(x, Tx1o, Tx1i, P2o, P2i, Wt,
                                                     bz, bh, wlin, blin, (float*)d_out);
}

// Round 5
// 198.934 us; speedup vs baseline: 2.7935x; 1.2454x over previous
//
#include <hip/hip_runtime.h>

#define N_NODES 50000
#define N_EDGES 800000
#define F_IN    32
#define F_OUT   64
#define PERIODS 12
#define C_FEAT  160   // [X, Tx1o, Tx1i, Tx2o, Tx2i] each 32 channels

#define NKEY    (2 * N_NODES)    // 100000 combined keys: fwd=col, rev=N+row
#define NBIN    782              // ceil(100000/128) — 128 keys per bin
#define NBLK_A  128
#define EPB     (N_EDGES / NBLK_A)   // 6250 edges per A-block (exact)
#define TOT     (2 * N_EDGES)        // 1.6M CSR entries
#define SCANA_N (NBIN * NBLK_A)      // 100096 = 391*256 exactly
#define SCANA_NB 391

typedef __attribute__((ext_vector_type(8))) short s16x8;
typedef __attribute__((ext_vector_type(4))) float f32x4;

static __device__ __forceinline__ ushort f2bf(float f) {
    unsigned u = __float_as_uint(f);
    unsigned r = (u + 0x7FFFu + ((u >> 16) & 1u)) >> 16;   // RNE
    return (ushort)r;
}

static __device__ __forceinline__ s16x8 pack8(float4 lo, float4 hi) {
    s16x8 r;
    r[0] = (short)f2bf(lo.x); r[1] = (short)f2bf(lo.y);
    r[2] = (short)f2bf(lo.z); r[3] = (short)f2bf(lo.w);
    r[4] = (short)f2bf(hi.x); r[5] = (short)f2bf(hi.y);
    r[6] = (short)f2bf(hi.z); r[7] = (short)f2bf(hi.w);
    return r;
}

// ---------------------------------------------------------------------------
// Pass A1: per-block LDS histogram of combined keys into 782 coarse bins.
// ---------------------------------------------------------------------------
__global__ __launch_bounds__(256) void k_histA(const int* __restrict__ ei,
                                               int* __restrict__ hist) {
    __shared__ int h[NBIN];
    int tid = threadIdx.x, blk = blockIdx.x;
    for (int i = tid; i < NBIN; i += 256) h[i] = 0;
    __syncthreads();
    int e0 = blk * EPB;
    for (int i = tid; i < EPB; i += 256) {
        int e = e0 + i;
        int r = ei[e];
        int c = ei[N_EDGES + e];
        atomicAdd(&h[c >> 7], 1);
        atomicAdd(&h[(N_NODES + r) >> 7], 1);
    }
    __syncthreads();
    for (int i = tid; i < NBIN; i += 256) hist[i * NBLK_A + blk] = h[i];
}

// ---------------------------------------------------------------------------
// Exclusive scan of hist[SCANA_N] -> scanA[SCANA_N]
// ---------------------------------------------------------------------------
__global__ __launch_bounds__(256) void k_scan1(const int* __restrict__ cnt,
                                               int* __restrict__ off,
                                               int* __restrict__ bsum) {
    __shared__ int lds[256];
    int g = blockIdx.x * 256 + threadIdx.x;
    int v = (g < SCANA_N) ? cnt[g] : 0;
    int orig = v;
    lds[threadIdx.x] = v;
    __syncthreads();
    for (int d = 1; d < 256; d <<= 1) {
        int t = (threadIdx.x >= d) ? lds[threadIdx.x - d] : 0;
        __syncthreads();
        lds[threadIdx.x] += t;
        __syncthreads();
    }
    if (g < SCANA_N) off[g] = lds[threadIdx.x] - orig;   // exclusive
    if (threadIdx.x == 255) bsum[blockIdx.x] = lds[threadIdx.x];
}

__global__ __launch_bounds__(512) void k_scan2(int* __restrict__ bsum) {
    __shared__ int lds[512];
    int t = threadIdx.x;
    int v = (t < SCANA_NB) ? bsum[t] : 0;
    int orig = v;
    lds[t] = v;
    __syncthreads();
    for (int d = 1; d < 512; d <<= 1) {
        int x = (t >= d) ? lds[t - d] : 0;
        __syncthreads();
        lds[t] += x;
        __syncthreads();
    }
    if (t < SCANA_NB) bsum[t] = lds[t] - orig;           // exclusive
}

__global__ __launch_bounds__(256) void k_scan3(int* __restrict__ off,
                                               const int* __restrict__ bsum) {
    int g = blockIdx.x * 256 + threadIdx.x;
    if (g < SCANA_N) off[g] += bsum[blockIdx.x];
}

// ---------------------------------------------------------------------------
// Pass A3: multi-split — place 8B items (key_low7 | src<<7, w) into bins.
// ---------------------------------------------------------------------------
__global__ __launch_bounds__(256) void k_binA(const int* __restrict__ ei,
                                              const float* __restrict__ ew,
                                              const int* __restrict__ scanA,
                                              uint2* __restrict__ binned) {
    __shared__ int cur[NBIN];
    int tid = threadIdx.x, blk = blockIdx.x;
    for (int i = tid; i < NBIN; i += 256) cur[i] = scanA[i * NBLK_A + blk];
    __syncthreads();
    int e0 = blk * EPB;
    for (int i = tid; i < EPB; i += 256) {
        int e = e0 + i;
        int r = ei[e];
        int c = ei[N_EDGES + e];
        unsigned wb = __float_as_uint(ew[e]);
        int k1 = c;               // fwd: grouped by col, src = row
        int k2 = N_NODES + r;     // rev: grouped by row, src = col
        int p1 = atomicAdd(&cur[k1 >> 7], 1);
        binned[p1] = make_uint2((unsigned)((k1 & 127) | (r << 7)), wb);
        int p2 = atomicAdd(&cur[k2 >> 7], 1);
        binned[p2] = make_uint2((unsigned)((k2 & 127) | (c << 7)), wb);
    }
}

// ---------------------------------------------------------------------------
// Pass B: per-bin counting sort (one block per bin, 128 keys/bin).
// Also computes weighted-degree sums -> inv[key] = 1/deg, and off[key].
// ---------------------------------------------------------------------------
__global__ __launch_bounds__(256) void k_sortbin(const uint2* __restrict__ binned,
                                                 const int* __restrict__ scanA,
                                                 int* __restrict__ csr,
                                                 int* __restrict__ off,
                                                 float* __restrict__ inv) {
    __shared__ int cnt[128];
    __shared__ int sc[128];
    __shared__ int cur[128];
    __shared__ float deg[128];
    int tid = threadIdx.x;
    int b   = blockIdx.x;
    int base = scanA[b * NBLK_A];
    int end  = (b + 1 < NBIN) ? scanA[(b + 1) * NBLK_A] : TOT;
    if (tid < 128) { cnt[tid] = 0; deg[tid] = 0.0f; }
    __syncthreads();
    for (int i = base + tid; i < end; i += 256) {
        uint2 it = binned[i];
        int kl = it.x & 127;
        atomicAdd(&cnt[kl], 1);
        atomicAdd(&deg[kl], __uint_as_float(it.y));
    }
    __syncthreads();
    if (tid < 128) sc[tid] = cnt[tid];
    __syncthreads();
    for (int d = 1; d < 128; d <<= 1) {
        int t = (tid >= d && tid < 128) ? sc[tid - d] : 0;
        __syncthreads();
        if (tid < 128) sc[tid] += t;
        __syncthreads();
    }
    if (tid < 128) cur[tid] = sc[tid] - cnt[tid];   // exclusive
    __syncthreads();
    for (int i = base + tid; i < end; i += 256) {
        uint2 it = binned[i];
        int kl = it.x & 127;
        int pos = atomicAdd(&cur[kl], 1);
        csr[base + pos] = (int)(it.x >> 7);
    }
    if (tid < 128) {
        int key = (b << 7) + tid;
        off[key] = base + sc[tid] - cnt[tid];
        inv[key] = 1.0f / deg[tid];                  // inf for deg 0: never read
    }
    // off[100000] sentinel auto-written by bin 781 (= TOT at key 100096? no:
    // keys 100000..100095 get off = base-of-tail = TOT since their cnt=0).
}

// ---------------------------------------------------------------------------
// Gather propagation, no atomics. idx in [0, 2N): first N = fwd, rest = rev.
// coef: fwd entry src=r needs 1/deg_out[r] = inv[N+src]; rev: inv[src].
// ---------------------------------------------------------------------------
__global__ __launch_bounds__(256) void k_gather(const int* __restrict__ off,
                                                const int* __restrict__ csr,
                                                const float* __restrict__ inv,
                                                const float* __restrict__ h_fwd,
                                                const float* __restrict__ h_rev,
                                                float* __restrict__ out_fwd,
                                                float* __restrict__ out_rev) {
    int tid = blockIdx.x * blockDim.x + threadIdx.x;
    int idx = tid >> 5;
    int f   = tid & 31;
    if (idx >= NKEY) return;
    bool fwd = idx < N_NODES;
    const float* h    = fwd ? h_fwd : h_rev;
    const float* itab = inv + (fwd ? N_NODES : 0);
    int beg = off[idx];
    int end = off[idx + 1];
    float acc = 0.0f;
    int j = beg;
    if (j < end) {
        int s = csr[j];
        float cv = itab[s];
        for (++j; j < end; ++j) {
            int s2 = csr[j];
            float cv2 = itab[s2];
            acc = fmaf(cv, h[s * F_IN + f], acc);
            s = s2; cv = cv2;
        }
        acc = fmaf(cv, h[s * F_IN + f], acc);
    }
    int v = fwd ? idx : idx - N_NODES;
    (fwd ? out_fwd : out_rev)[v * F_IN + f] = acc;
}

// ---------------------------------------------------------------------------
// Build bf16 transposed weight Wt[o][k], o in [0,128): z cols then h cols,
// k in [0,160). Plain row-major, stride 160 (rows 16B-aligned: 320B).
// Source layout (2,3,96,64); rows 32..95 dead (H0==0).
// ---------------------------------------------------------------------------
__global__ __launch_bounds__(256) void k_prep(const float* __restrict__ wz,
                                              const float* __restrict__ wh,
                                              ushort* __restrict__ Wt) {
    int tid = blockIdx.x * blockDim.x + threadIdx.x;
    if (tid >= 128 * C_FEAT) return;
    int o = tid / C_FEAT;
    int k = tid % C_FEAT;
    int seg = k >> 5;
    int cc  = k & 31;
    const float* src = (o < 64) ? wz : wh;
    int oo = o & 63;
    float val;
    if (seg == 0)      val = src[(0 * 96 + cc) * 64 + oo] + src[(3 * 96 + cc) * 64 + oo];
    else if (seg == 1) val = src[(1 * 96 + cc) * 64 + oo];
    else if (seg == 2) val = src[(4 * 96 + cc) * 64 + oo];
    else if (seg == 3) val = src[(2 * 96 + cc) * 64 + oo];
    else               val = src[(5 * 96 + cc) * 64 + oo];
    Wt[tid] = f2bf(val);
}

// ---------------------------------------------------------------------------
// MFMA epilogue: [32 nodes x 160] x [160 x 128], B in registers, A direct
// from global (aligned float4 pairs -> bf16 pack). Wave w: row-tile w&1,
// z cols 32*(w>>1)+[0,32) and h cols 64+32*(w>>1)+[0,32)  => in-register
// gating. LDS only for the relu'd H (32x66 f32) feeding the 64x12 head.
// ---------------------------------------------------------------------------
__global__ __launch_bounds__(256, 3) void k_final(
        const float* __restrict__ X,
        const float* __restrict__ Tx1o,
        const float* __restrict__ Tx1i,
        const float* __restrict__ P2o,
        const float* __restrict__ P2i,
        const ushort* __restrict__ Wt,
        const float* __restrict__ bz,
        const float* __restrict__ bh,
        const float* __restrict__ wlin,
        const float* __restrict__ blin,
        float* __restrict__ out) {
    __shared__ float r_lds[32][66];                    // 8448 B total LDS
    int tid   = threadIdx.x;
    int node0 = blockIdx.x * 32;
    int w  = tid >> 6;
    int l  = tid & 63;
    int lr = l & 15;
    int lg = l >> 4;
    int rt = w & 1;             // row tile (16 nodes)
    int cb = (w >> 1) * 32;     // col base within the 64 z (and 64 h) cols

    // --- B fragments in registers: t in {z-ct0, z-ct1, h-ct0, h-ct1} ---
    s16x8 bf[4][5];
#pragma unroll
    for (int t = 0; t < 4; ++t) {
        int col = cb + (t & 1) * 16 + lr + ((t >> 1) ? 64 : 0);
        const ushort* wp = Wt + col * C_FEAT + lg * 8;
#pragma unroll
        for (int kb = 0; kb < 5; ++kb)
            bf[t][kb] = *(const s16x8*)(wp + kb * 32);
    }

    // --- A fragments direct from global (row clamped; tail rows masked later)
    int row = node0 + rt * 16 + lr;
    if (row >= N_NODES) row = N_NODES - 1;
    int rbase = row * F_IN + lg * 8;
    float4 x0  = *(const float4*)&X[rbase],    x1  = *(const float4*)&X[rbase + 4];
    float4 o0  = *(const float4*)&Tx1o[rbase], o1  = *(const float4*)&Tx1o[rbase + 4];
    float4 i0  = *(const float4*)&Tx1i[rbase], i1  = *(const float4*)&Tx1i[rbase + 4];
    float4 p0  = *(const float4*)&P2o[rbase],  p1  = *(const float4*)&P2o[rbase + 4];
    float4 q0  = *(const float4*)&P2i[rbase],  q1  = *(const float4*)&P2i[rbase + 4];
    s16x8 a[5];
    a[0] = pack8(x0, x1);
    a[1] = pack8(o0, o1);
    a[2] = pack8(i0, i1);
    float4 t3l = make_float4(2.f*p0.x-x0.x, 2.f*p0.y-x0.y, 2.f*p0.z-x0.z, 2.f*p0.w-x0.w);
    float4 t3h = make_float4(2.f*p1.x-x1.x, 2.f*p1.y-x1.y, 2.f*p1.z-x1.z, 2.f*p1.w-x1.w);
    float4 t4l = make_float4(2.f*q0.x-x0.x, 2.f*q0.y-x0.y, 2.f*q0.z-x0.z, 2.f*q0.w-x0.w);
    float4 t4h = make_float4(2.f*q1.x-x1.x, 2.f*q1.y-x1.y, 2.f*q1.z-x1.z, 2.f*q1.w-x1.w);
    a[3] = pack8(t3l, t3h);
    a[4] = pack8(t4l, t4h);

    // --- MFMA: 4 accs x 5 K-blocks ---
    f32x4 acc[4] = {};
#pragma unroll
    for (int kb = 0; kb < 5; ++kb) {
        acc[0] = __builtin_amdgcn_mfma_f32_16x16x32_bf16(a[kb], bf[0][kb], acc[0], 0, 0, 0);
        acc[1] = __builtin_amdgcn_mfma_f32_16x16x32_bf16(a[kb], bf[1][kb], acc[1], 0, 0, 0);
        acc[2] = __builtin_amdgcn_mfma_f32_16x16x32_bf16(a[kb], bf[2][kb], acc[2], 0, 0, 0);
        acc[3] = __builtin_amdgcn_mfma_f32_16x16x32_bf16(a[kb], bf[3][kb], acc[3], 0, 0, 0);
    }

    // --- in-register gating; D layout: col = lane&15, row = lg*4 + q ---
#pragma unroll
    for (int ct = 0; ct < 2; ++ct) {
        int o = cb + ct * 16 + lr;
        float bzv = bz[o];
        float bhv = bh[o];
#pragma unroll
        for (int qq = 0; qq < 4; ++qq) {
            float zp = acc[ct][qq] + bzv;
            float hp = acc[2 + ct][qq] + bhv;
            float z  = 1.0f / (1.0f + __expf(-zp));
            float e2 = __expf(2.0f * hp);
            float th = 1.0f - 2.0f / (e2 + 1.0f);    // tanh(hp)
            r_lds[rt * 16 + lg * 4 + qq][o] = fmaxf((1.0f - z) * th, 0.0f);
        }
    }
    __syncthreads();

    // --- 64x12 head ---
    for (int i = tid; i < 32 * PERIODS; i += 256) {
        int n = i / PERIODS;
        int p = i % PERIODS;
        int v = node0 + n;
        if (v < N_NODES) {
            float acc2 = blin[p];
#pragma unroll
            for (int oo = 0; oo < F_OUT; ++oo)
                acc2 = fmaf(r_lds[n][oo], wlin[oo * PERIODS + p], acc2);
            out[v * PERIODS + p] = acc2;
        }
    }
}

// ---------------------------------------------------------------------------
extern "C" void kernel_launch(void* const* d_in, const int* in_sizes, int n_in,
                              void* d_out, int out_size, void* d_ws, size_t ws_size,
                              hipStream_t stream) {
    const float* x    = (const float*)d_in[0];
    const int*   ei   = (const int*)d_in[1];
    const float* ew   = (const float*)d_in[2];
    const float* wz   = (const float*)d_in[3];
    const float* bz   = (const float*)d_in[4];
    // d_in[5], d_in[6] = w_r, b_r : provably unused (H0 == 0)
    const float* wh   = (const float*)d_in[7];
    const float* bh   = (const float*)d_in[8];
    const float* wlin = (const float*)d_in[9];
    const float* blin = (const float*)d_in[10];

    // workspace layout — everything write-before-read; no memset needed.
    // All region sizes are multiples of 16B so Wt/float4 loads stay aligned.
    int*    histA  = (int*)d_ws;                       // [100096]
    int*    scanA  = histA + SCANA_N;                  // [100096]
    int*    bsum   = scanA + SCANA_N;                  // [512]
    uint2*  binned = (uint2*)(bsum + 512);             // [1.6M]
    int*    csr    = (int*)(binned + TOT);             // [1.6M]
    int*    off    = csr + TOT;                        // [100100]
    float*  inv    = (float*)(off + 100100);           // [100096]
    float*  Tx1o   = inv + SCANA_N;                    // [N*32] x4
    float*  Tx1i   = Tx1o + (size_t)N_NODES * F_IN;
    float*  P2o    = Tx1i + (size_t)N_NODES * F_IN;
    float*  P2i    = P2o + (size_t)N_NODES * F_IN;
    ushort* Wt     = (ushort*)(P2i + (size_t)N_NODES * F_IN);  // [128*160] bf16

    k_prep<<<(128 * C_FEAT + 255) / 256, 256, 0, stream>>>(wz, wh, Wt);

    // CSR build: histogram -> scan -> multi-split -> per-bin counting sort
    k_histA<<<NBLK_A, 256, 0, stream>>>(ei, histA);
    k_scan1<<<SCANA_NB, 256, 0, stream>>>(histA, scanA, bsum);
    k_scan2<<<1, 512, 0, stream>>>(bsum);
    k_scan3<<<SCANA_NB, 256, 0, stream>>>(scanA, bsum);
    k_binA<<<NBLK_A, 256, 0, stream>>>(ei, ew, scanA, binned);
    k_sortbin<<<NBIN, 256, 0, stream>>>(binned, scanA, csr, off, inv);

    // step 1: Tx1o = prop_fwd(X), Tx1i = prop_rev(X)
    k_gather<<<(NKEY * 32) / 256, 256, 0, stream>>>(off, csr, inv, x, x, Tx1o, Tx1i);
    // step 2: P2o = prop_fwd(Tx1o), P2i = prop_rev(Tx1i); Tx2 = 2*P2 - X in k_final
    k_gather<<<(NKEY * 32) / 256, 256, 0, stream>>>(off, csr, inv, Tx1o, Tx1i, P2o, P2i);

    k_final<<<(N_NODES + 31) / 32, 256, 0, stream>>>(x, Tx1o, Tx1i, P2o, P2i, Wt,
                                                     bz, bh, wlin, blin, (float*)d_out);
}

// Round 6
// 177.561 us; speedup vs baseline: 3.1298x; 1.1204x over previous
//
#include <hip/hip_runtime.h>

#define N_NODES 50000
#define N_EDGES 800000
#define F_IN    32
#define F_OUT   64
#define PERIODS 12
#define C_FEAT  160   // [X, Tx1o, Tx1i, Tx2o, Tx2i] each 32 channels

#define NKEY    (2 * N_NODES)    // 100000 combined keys: fwd=col, rev=N+row
#define NBIN    782              // ceil(100000/128) — 128 keys per bin
#define NBLK_A  128
#define EPB     (N_EDGES / NBLK_A)   // 6250 edges per A-block (exact)
#define TOT     (2 * N_EDGES)        // 1.6M CSR entries
#define SCANA_N (NBIN * NBLK_A)      // 100096 = 391*256 exactly
#define SCANA_NB 391
#define NGRP    (N_NODES / 8)        // 6250 key-groups per direction

typedef __attribute__((ext_vector_type(8))) short s16x8;
typedef __attribute__((ext_vector_type(4))) float f32x4;

static __device__ __forceinline__ ushort f2bf(float f) {
    unsigned u = __float_as_uint(f);
    unsigned r = (u + 0x7FFFu + ((u >> 16) & 1u)) >> 16;   // RNE
    return (ushort)r;
}
static __device__ __forceinline__ float bf2f(ushort u) {
    return __uint_as_float((unsigned)u << 16);
}

static __device__ __forceinline__ s16x8 pack8(float4 lo, float4 hi) {
    s16x8 r;
    r[0] = (short)f2bf(lo.x); r[1] = (short)f2bf(lo.y);
    r[2] = (short)f2bf(lo.z); r[3] = (short)f2bf(lo.w);
    r[4] = (short)f2bf(hi.x); r[5] = (short)f2bf(hi.y);
    r[6] = (short)f2bf(hi.z); r[7] = (short)f2bf(hi.w);
    return r;
}

// ---------------------------------------------------------------------------
// X -> bf16 copy (gather source table; 3.2 MB fits per-XCD L2)
// ---------------------------------------------------------------------------
__global__ __launch_bounds__(256) void k_xbf(const float* __restrict__ X,
                                             ushort* __restrict__ Xb) {
    int t = blockIdx.x * 256 + threadIdx.x;
    if (t * 4 >= N_NODES * F_IN) return;
    float4 v = *(const float4*)&X[t * 4];
    ushort4 o;
    o.x = f2bf(v.x); o.y = f2bf(v.y); o.z = f2bf(v.z); o.w = f2bf(v.w);
    *(ushort4*)&Xb[t * 4] = o;
}

// ---------------------------------------------------------------------------
// Pass A1: per-block LDS histogram of combined keys into 782 coarse bins.
// ---------------------------------------------------------------------------
__global__ __launch_bounds__(256) void k_histA(const int* __restrict__ ei,
                                               int* __restrict__ hist) {
    __shared__ int h[NBIN];
    int tid = threadIdx.x, blk = blockIdx.x;
    for (int i = tid; i < NBIN; i += 256) h[i] = 0;
    __syncthreads();
    int e0 = blk * EPB;
    for (int i = tid; i < EPB; i += 256) {
        int e = e0 + i;
        int r = ei[e];
        int c = ei[N_EDGES + e];
        atomicAdd(&h[c >> 7], 1);
        atomicAdd(&h[(N_NODES + r) >> 7], 1);
    }
    __syncthreads();
    for (int i = tid; i < NBIN; i += 256) hist[i * NBLK_A + blk] = h[i];
}

// ---------------------------------------------------------------------------
// Exclusive scan of hist[SCANA_N]: per-256-block scan + block sums scan.
// Cross-block offset (bsum) is folded in by consumers: scanF(i)=scanA[i]+bsum[i>>8].
// ---------------------------------------------------------------------------
__global__ __launch_bounds__(256) void k_scan1(const int* __restrict__ cnt,
                                               int* __restrict__ scanA,
                                               int* __restrict__ bsum) {
    __shared__ int lds[256];
    int g = blockIdx.x * 256 + threadIdx.x;
    int v = (g < SCANA_N) ? cnt[g] : 0;
    int orig = v;
    lds[threadIdx.x] = v;
    __syncthreads();
    for (int d = 1; d < 256; d <<= 1) {
        int t = (threadIdx.x >= d) ? lds[threadIdx.x - d] : 0;
        __syncthreads();
        lds[threadIdx.x] += t;
        __syncthreads();
    }
    if (g < SCANA_N) scanA[g] = lds[threadIdx.x] - orig;   // exclusive, block-local
    if (threadIdx.x == 255) bsum[blockIdx.x] = lds[threadIdx.x];
}

__global__ __launch_bounds__(512) void k_scan2(int* __restrict__ bsum) {
    __shared__ int lds[512];
    int t = threadIdx.x;
    int v = (t < SCANA_NB) ? bsum[t] : 0;
    int orig = v;
    lds[t] = v;
    __syncthreads();
    for (int d = 1; d < 512; d <<= 1) {
        int x = (t >= d) ? lds[t - d] : 0;
        __syncthreads();
        lds[t] += x;
        __syncthreads();
    }
    if (t < SCANA_NB) bsum[t] = lds[t] - orig;             // exclusive
}

// ---------------------------------------------------------------------------
// Pass A3: multi-split — place 8B items (key_low7 | src<<7, w) into bins.
// ---------------------------------------------------------------------------
__global__ __launch_bounds__(256) void k_binA(const int* __restrict__ ei,
                                              const float* __restrict__ ew,
                                              const int* __restrict__ scanA,
                                              const int* __restrict__ bsum,
                                              uint2* __restrict__ binned) {
    __shared__ int cur[NBIN];
    int tid = threadIdx.x, blk = blockIdx.x;
    for (int i = tid; i < NBIN; i += 256) {
        int idx = i * NBLK_A + blk;
        cur[i] = scanA[idx] + bsum[idx >> 8];
    }
    __syncthreads();
    int e0 = blk * EPB;
    for (int i = tid; i < EPB; i += 256) {
        int e = e0 + i;
        int r = ei[e];
        int c = ei[N_EDGES + e];
        unsigned wb = __float_as_uint(ew[e]);
        int k1 = c;               // fwd: grouped by col, src = row
        int k2 = N_NODES + r;     // rev: grouped by row, src = col
        int p1 = atomicAdd(&cur[k1 >> 7], 1);
        binned[p1] = make_uint2((unsigned)((k1 & 127) | (r << 7)), wb);
        int p2 = atomicAdd(&cur[k2 >> 7], 1);
        binned[p2] = make_uint2((unsigned)((k2 & 127) | (c << 7)), wb);
    }
}

// ---------------------------------------------------------------------------
// Pass B: per-bin counting sort (one block per bin, 128 keys/bin).
// Also computes weighted-degree sums -> inv[key] = 1/deg, and off[key].
// ---------------------------------------------------------------------------
__global__ __launch_bounds__(256) void k_sortbin(const uint2* __restrict__ binned,
                                                 const int* __restrict__ scanA,
                                                 const int* __restrict__ bsum,
                                                 int* __restrict__ csr,
                                                 int* __restrict__ off,
                                                 float* __restrict__ inv) {
    __shared__ int cnt[128];
    __shared__ int sc[128];
    __shared__ int cur[128];
    __shared__ float deg[128];
    int tid = threadIdx.x;
    int b   = blockIdx.x;
    int i0 = b * NBLK_A;
    int base = scanA[i0] + bsum[i0 >> 8];
    int end;
    if (b + 1 < NBIN) {
        int i1 = (b + 1) * NBLK_A;
        end = scanA[i1] + bsum[i1 >> 8];
    } else end = TOT;
    if (tid < 128) { cnt[tid] = 0; deg[tid] = 0.0f; }
    __syncthreads();
    for (int i = base + tid; i < end; i += 256) {
        uint2 it = binned[i];
        int kl = it.x & 127;
        atomicAdd(&cnt[kl], 1);
        atomicAdd(&deg[kl], __uint_as_float(it.y));
    }
    __syncthreads();
    if (tid < 128) sc[tid] = cnt[tid];
    __syncthreads();
    for (int d = 1; d < 128; d <<= 1) {
        int t = (tid >= d && tid < 128) ? sc[tid - d] : 0;
        __syncthreads();
        if (tid < 128) sc[tid] += t;
        __syncthreads();
    }
    if (tid < 128) cur[tid] = sc[tid] - cnt[tid];   // exclusive
    __syncthreads();
    for (int i = base + tid; i < end; i += 256) {
        uint2 it = binned[i];
        int kl = it.x & 127;
        int pos = atomicAdd(&cur[kl], 1);
        csr[base + pos] = (int)(it.x >> 7);
    }
    if (tid < 128) {
        int key = (b << 7) + tid;
        off[key] = base + sc[tid] - cnt[tid];
        inv[key] = 1.0f / deg[tid];                  // inf for deg 0: never read
    }
    // keys 100000..100095 (bin 781 padding) get off = TOT -> valid sentinel.
}

// ---------------------------------------------------------------------------
// Gather propagation over bf16 source tables; no atomics.
// Direction-split XCD swizzle: blocks with (blockIdx&7)<4 do fwd keys, rest
// rev keys -> each XCD's gather working set is one 3.2 MB table (fits L2).
// 32 lanes per key; one 64B line per CSR entry; 2-unrolled for MLP.
// WRITE_BF=1: bf16 output (step 1); 0: fp32 output (step 2).
// ---------------------------------------------------------------------------
template<int WRITE_BF>
__global__ __launch_bounds__(256) void k_gather(const int* __restrict__ off,
                                                const int* __restrict__ csr,
                                                const float* __restrict__ inv,
                                                const ushort* __restrict__ hb_fwd,
                                                const ushort* __restrict__ hb_rev,
                                                ushort* __restrict__ ob_fwd,
                                                ushort* __restrict__ ob_rev,
                                                float* __restrict__ of_fwd,
                                                float* __restrict__ of_rev) {
    int g    = blockIdx.x;
    int xcd  = g & 7;
    int slot = g >> 3;
    bool fwd = xcd < 4;
    int grp  = slot * 4 + (xcd & 3);
    if (grp >= NGRP) return;
    int kl  = threadIdx.x >> 5;
    int f   = threadIdx.x & 31;
    int key = grp * 8 + kl;                   // node id within direction
    int idx = fwd ? key : (N_NODES + key);
    const ushort* hb   = fwd ? hb_fwd : hb_rev;
    const float*  itab = inv + (fwd ? N_NODES : 0);
    int beg = off[idx];
    int end = off[idx + 1];
    float acc = 0.0f;
    int j = beg;
    for (; j + 1 < end; j += 2) {
        int s0 = csr[j], s1 = csr[j + 1];
        float c0 = itab[s0], c1 = itab[s1];
        float h0 = bf2f(hb[s0 * F_IN + f]);
        float h1 = bf2f(hb[s1 * F_IN + f]);
        acc = fmaf(c0, h0, acc);
        acc = fmaf(c1, h1, acc);
    }
    if (j < end) {
        int s0 = csr[j];
        acc = fmaf(itab[s0], bf2f(hb[s0 * F_IN + f]), acc);
    }
    if (WRITE_BF) (fwd ? ob_fwd : ob_rev)[key * F_IN + f] = f2bf(acc);
    else          (fwd ? of_fwd : of_rev)[key * F_IN + f] = acc;
}

// ---------------------------------------------------------------------------
// Build bf16 transposed weight Wt[o][k], o in [0,128): z cols then h cols.
// Source layout (2,3,96,64); rows 32..95 dead (H0==0).
// ---------------------------------------------------------------------------
__global__ __launch_bounds__(256) void k_prep(const float* __restrict__ wz,
                                              const float* __restrict__ wh,
                                              ushort* __restrict__ Wt) {
    int tid = blockIdx.x * blockDim.x + threadIdx.x;
    if (tid >= 128 * C_FEAT) return;
    int o = tid / C_FEAT;
    int k = tid % C_FEAT;
    int seg = k >> 5;
    int cc  = k & 31;
    const float* src = (o < 64) ? wz : wh;
    int oo = o & 63;
    float val;
    if (seg == 0)      val = src[(0 * 96 + cc) * 64 + oo] + src[(3 * 96 + cc) * 64 + oo];
    else if (seg == 1) val = src[(1 * 96 + cc) * 64 + oo];
    else if (seg == 2) val = src[(4 * 96 + cc) * 64 + oo];
    else if (seg == 3) val = src[(2 * 96 + cc) * 64 + oo];
    else               val = src[(5 * 96 + cc) * 64 + oo];
    Wt[tid] = f2bf(val);
}

// ---------------------------------------------------------------------------
// MFMA epilogue: [32 nodes x 160] x [160 x 128], B in registers, A direct
// from global. Tx1 fragments load straight from bf16 tables (s16x8).
// In-register gating; LDS only for the relu'd H feeding the 64x12 head.
// ---------------------------------------------------------------------------
__global__ __launch_bounds__(256, 3) void k_final(
        const float* __restrict__ X,
        const ushort* __restrict__ Tx1o,
        const ushort* __restrict__ Tx1i,
        const float* __restrict__ P2o,
        const float* __restrict__ P2i,
        const ushort* __restrict__ Wt,
        const float* __restrict__ bz,
        const float* __restrict__ bh,
        const float* __restrict__ wlin,
        const float* __restrict__ blin,
        float* __restrict__ out) {
    __shared__ float r_lds[32][66];                    // 8448 B total LDS
    int tid   = threadIdx.x;
    int node0 = blockIdx.x * 32;
    int w  = tid >> 6;
    int l  = tid & 63;
    int lr = l & 15;
    int lg = l >> 4;
    int rt = w & 1;             // row tile (16 nodes)
    int cb = (w >> 1) * 32;     // col base within the 64 z (and 64 h) cols

    // --- B fragments in registers: t in {z-ct0, z-ct1, h-ct0, h-ct1} ---
    s16x8 bf[4][5];
#pragma unroll
    for (int t = 0; t < 4; ++t) {
        int col = cb + (t & 1) * 16 + lr + ((t >> 1) ? 64 : 0);
        const ushort* wp = Wt + col * C_FEAT + lg * 8;
#pragma unroll
        for (int kb = 0; kb < 5; ++kb)
            bf[t][kb] = *(const s16x8*)(wp + kb * 32);
    }

    // --- A fragments (row clamped; tail rows masked at write) ---
    int row = node0 + rt * 16 + lr;
    if (row >= N_NODES) row = N_NODES - 1;
    int rbase = row * F_IN + lg * 8;
    float4 x0 = *(const float4*)&X[rbase],   x1 = *(const float4*)&X[rbase + 4];
    float4 p0 = *(const float4*)&P2o[rbase], p1 = *(const float4*)&P2o[rbase + 4];
    float4 q0 = *(const float4*)&P2i[rbase], q1 = *(const float4*)&P2i[rbase + 4];
    s16x8 a[5];
    a[0] = pack8(x0, x1);
    a[1] = *(const s16x8*)&Tx1o[rbase];
    a[2] = *(const s16x8*)&Tx1i[rbase];
    float4 t3l = make_float4(2.f*p0.x-x0.x, 2.f*p0.y-x0.y, 2.f*p0.z-x0.z, 2.f*p0.w-x0.w);
    float4 t3h = make_float4(2.f*p1.x-x1.x, 2.f*p1.y-x1.y, 2.f*p1.z-x1.z, 2.f*p1.w-x1.w);
    float4 t4l = make_float4(2.f*q0.x-x0.x, 2.f*q0.y-x0.y, 2.f*q0.z-x0.z, 2.f*q0.w-x0.w);
    float4 t4h = make_float4(2.f*q1.x-x1.x, 2.f*q1.y-x1.y, 2.f*q1.z-x1.z, 2.f*q1.w-x1.w);
    a[3] = pack8(t3l, t3h);
    a[4] = pack8(t4l, t4h);

    // --- MFMA: 4 accs x 5 K-blocks ---
    f32x4 acc[4] = {};
#pragma unroll
    for (int kb = 0; kb < 5; ++kb) {
        acc[0] = __builtin_amdgcn_mfma_f32_16x16x32_bf16(a[kb], bf[0][kb], acc[0], 0, 0, 0);
        acc[1] = __builtin_amdgcn_mfma_f32_16x16x32_bf16(a[kb], bf[1][kb], acc[1], 0, 0, 0);
        acc[2] = __builtin_amdgcn_mfma_f32_16x16x32_bf16(a[kb], bf[2][kb], acc[2], 0, 0, 0);
        acc[3] = __builtin_amdgcn_mfma_f32_16x16x32_bf16(a[kb], bf[3][kb], acc[3], 0, 0, 0);
    }

    // --- in-register gating; D layout: col = lane&15, row = lg*4 + q ---
#pragma unroll
    for (int ct = 0; ct < 2; ++ct) {
        int o = cb + ct * 16 + lr;
        float bzv = bz[o];
        float bhv = bh[o];
#pragma unroll
        for (int qq = 0; qq < 4; ++qq) {
            float zp = acc[ct][qq] + bzv;
            float hp = acc[2 + ct][qq] + bhv;
            float z  = 1.0f / (1.0f + __expf(-zp));
            float e2 = __expf(2.0f * hp);
            float th = 1.0f - 2.0f / (e2 + 1.0f);    // tanh(hp)
            r_lds[rt * 16 + lg * 4 + qq][o] = fmaxf((1.0f - z) * th, 0.0f);
        }
    }
    __syncthreads();

    // --- 64x12 head ---
    for (int i = tid; i < 32 * PERIODS; i += 256) {
        int n = i / PERIODS;
        int p = i % PERIODS;
        int v = node0 + n;
        if (v < N_NODES) {
            float acc2 = blin[p];
#pragma unroll
            for (int oo = 0; oo < F_OUT; ++oo)
                acc2 = fmaf(r_lds[n][oo], wlin[oo * PERIODS + p], acc2);
            out[v * PERIODS + p] = acc2;
        }
    }
}

// ---------------------------------------------------------------------------
extern "C" void kernel_launch(void* const* d_in, const int* in_sizes, int n_in,
                              void* d_out, int out_size, void* d_ws, size_t ws_size,
                              hipStream_t stream) {
    const float* x    = (const float*)d_in[0];
    const int*   ei   = (const int*)d_in[1];
    const float* ew   = (const float*)d_in[2];
    const float* wz   = (const float*)d_in[3];
    const float* bz   = (const float*)d_in[4];
    // d_in[5], d_in[6] = w_r, b_r : provably unused (H0 == 0)
    const float* wh   = (const float*)d_in[7];
    const float* bh   = (const float*)d_in[8];
    const float* wlin = (const float*)d_in[9];
    const float* blin = (const float*)d_in[10];

    // workspace layout — everything write-before-read; no memset needed.
    // All region byte-offsets are multiples of 16.
    int*    histA  = (int*)d_ws;                       // [100096]
    int*    scanA  = histA + SCANA_N;                  // [100096]
    int*    bsum   = scanA + SCANA_N;                  // [512]
    uint2*  binned = (uint2*)(bsum + 512);             // [1.6M]
    int*    csr    = (int*)(binned + TOT);             // [1.6M]
    int*    off    = csr + TOT;                        // [100100]
    float*  inv    = (float*)(off + 100100);           // [100096]
    ushort* X_bf   = (ushort*)(inv + SCANA_N);         // [1.6M] bf16
    ushort* T1o_b  = X_bf + (size_t)N_NODES * F_IN;    // [1.6M] bf16
    ushort* T1i_b  = T1o_b + (size_t)N_NODES * F_IN;   // [1.6M] bf16
    float*  P2o    = (float*)(T1i_b + (size_t)N_NODES * F_IN);  // [1.6M] f32
    float*  P2i    = P2o + (size_t)N_NODES * F_IN;     // [1.6M] f32
    ushort* Wt     = (ushort*)(P2i + (size_t)N_NODES * F_IN);   // [128*160] bf16

    k_prep<<<(128 * C_FEAT + 255) / 256, 256, 0, stream>>>(wz, wh, Wt);
    k_xbf<<<(N_NODES * F_IN / 4 + 255) / 256, 256, 0, stream>>>(x, X_bf);

    // CSR build: histogram -> scan (2 kernels, bsum folded by consumers) ->
    // multi-split -> per-bin counting sort
    k_histA<<<NBLK_A, 256, 0, stream>>>(ei, histA);
    k_scan1<<<SCANA_NB, 256, 0, stream>>>(histA, scanA, bsum);
    k_scan2<<<1, 512, 0, stream>>>(bsum);
    k_binA<<<NBLK_A, 256, 0, stream>>>(ei, ew, scanA, bsum, binned);
    k_sortbin<<<NBIN, 256, 0, stream>>>(binned, scanA, bsum, csr, off, inv);

    int ggrid = 8 * ((NGRP + 3) / 4);   // 12504 blocks, direction-split swizzle
    // step 1: Tx1o/Tx1i = prop(X)  (bf16 in, bf16 out)
    k_gather<1><<<ggrid, 256, 0, stream>>>(off, csr, inv, X_bf, X_bf,
                                           T1o_b, T1i_b, nullptr, nullptr);
    // step 2: P2o/P2i = prop(Tx1)  (bf16 in, fp32 out); Tx2 = 2*P2 - X in k_final
    k_gather<0><<<ggrid, 256, 0, stream>>>(off, csr, inv, T1o_b, T1i_b,
                                           nullptr, nullptr, P2o, P2i);

    k_final<<<(N_NODES + 31) / 32, 256, 0, stream>>>(x, T1o_b, T1i_b, P2o, P2i, Wt,
                                                     bz, bh, wlin, blin, (float*)d_out);
}

// Round 7
// 157.661 us; speedup vs baseline: 3.5248x; 1.1262x over previous
//
#include <hip/hip_runtime.h>

#define N_NODES 50000
#define N_EDGES 800000
#define F_IN    32
#define F_OUT   64
#define PERIODS 12
#define C_FEAT  160   // [X, Tx1o, Tx1i, Tx2o, Tx2i] each 32 channels

#define NKEY    (2 * N_NODES)    // 100000 combined keys: fwd=col, rev=N+row
#define NBIN    782              // ceil(100000/128) — 128 keys per bin
#define NBLK_A  128
#define EPB     (N_EDGES / NBLK_A)   // 6250 edges per A-block (exact)
#define TOT     (2 * N_EDGES)        // 1.6M CSR entries
#define SCANA_N (NBIN * NBLK_A)      // 100096 = 391*256 exactly
#define SCANA_NB 391
#define NGRP    (N_NODES / 8)        // 6250 key-groups per direction
#define NF      ((size_t)N_NODES * F_IN)

typedef __attribute__((ext_vector_type(8))) short s16x8;
typedef __attribute__((ext_vector_type(4))) float f32x4;

static __device__ __forceinline__ ushort f2bf(float f) {
    unsigned u = __float_as_uint(f);
    unsigned r = (u + 0x7FFFu + ((u >> 16) & 1u)) >> 16;   // RNE
    return (ushort)r;
}
static __device__ __forceinline__ float bf2f(ushort u) {
    return __uint_as_float((unsigned)u << 16);
}

static __device__ __forceinline__ s16x8 pack8(float4 lo, float4 hi) {
    s16x8 r;
    r[0] = (short)f2bf(lo.x); r[1] = (short)f2bf(lo.y);
    r[2] = (short)f2bf(lo.z); r[3] = (short)f2bf(lo.w);
    r[4] = (short)f2bf(hi.x); r[5] = (short)f2bf(hi.y);
    r[6] = (short)f2bf(hi.z); r[7] = (short)f2bf(hi.w);
    return r;
}

// ---------------------------------------------------------------------------
// Pass A1: per-block LDS histogram of combined keys into 782 coarse bins.
// ---------------------------------------------------------------------------
__global__ __launch_bounds__(256) void k_histA(const int* __restrict__ ei,
                                               int* __restrict__ hist) {
    __shared__ int h[NBIN];
    int tid = threadIdx.x, blk = blockIdx.x;
    for (int i = tid; i < NBIN; i += 256) h[i] = 0;
    __syncthreads();
    int e0 = blk * EPB;
    for (int i = tid; i < EPB; i += 256) {
        int e = e0 + i;
        int r = ei[e];
        int c = ei[N_EDGES + e];
        atomicAdd(&h[c >> 7], 1);
        atomicAdd(&h[(N_NODES + r) >> 7], 1);
    }
    __syncthreads();
    for (int i = tid; i < NBIN; i += 256) hist[i * NBLK_A + blk] = h[i];
}

// ---------------------------------------------------------------------------
// Exclusive scan of hist[SCANA_N]; bsum folded in by consumers.
// ---------------------------------------------------------------------------
__global__ __launch_bounds__(256) void k_scan1(const int* __restrict__ cnt,
                                               int* __restrict__ scanA,
                                               int* __restrict__ bsum) {
    __shared__ int lds[256];
    int g = blockIdx.x * 256 + threadIdx.x;
    int v = (g < SCANA_N) ? cnt[g] : 0;
    int orig = v;
    lds[threadIdx.x] = v;
    __syncthreads();
    for (int d = 1; d < 256; d <<= 1) {
        int t = (threadIdx.x >= d) ? lds[threadIdx.x - d] : 0;
        __syncthreads();
        lds[threadIdx.x] += t;
        __syncthreads();
    }
    if (g < SCANA_N) scanA[g] = lds[threadIdx.x] - orig;   // exclusive, block-local
    if (threadIdx.x == 255) bsum[blockIdx.x] = lds[threadIdx.x];
}

__global__ __launch_bounds__(512) void k_scan2(int* __restrict__ bsum) {
    __shared__ int lds[512];
    int t = threadIdx.x;
    int v = (t < SCANA_NB) ? bsum[t] : 0;
    int orig = v;
    lds[t] = v;
    __syncthreads();
    for (int d = 1; d < 512; d <<= 1) {
        int x = (t >= d) ? lds[t - d] : 0;
        __syncthreads();
        lds[t] += x;
        __syncthreads();
    }
    if (t < SCANA_NB) bsum[t] = lds[t] - orig;             // exclusive
}

// ---------------------------------------------------------------------------
// Pass A3: multi-split — place 8B items (key_low7 | src<<7, w) into bins.
// ---------------------------------------------------------------------------
__global__ __launch_bounds__(256) void k_binA(const int* __restrict__ ei,
                                              const float* __restrict__ ew,
                                              const int* __restrict__ scanA,
                                              const int* __restrict__ bsum,
                                              uint2* __restrict__ binned) {
    __shared__ int cur[NBIN];
    int tid = threadIdx.x, blk = blockIdx.x;
    for (int i = tid; i < NBIN; i += 256) {
        int idx = i * NBLK_A + blk;
        cur[i] = scanA[idx] + bsum[idx >> 8];
    }
    __syncthreads();
    int e0 = blk * EPB;
    for (int i = tid; i < EPB; i += 256) {
        int e = e0 + i;
        int r = ei[e];
        int c = ei[N_EDGES + e];
        unsigned wb = __float_as_uint(ew[e]);
        int k1 = c;               // fwd: grouped by col, src = row
        int k2 = N_NODES + r;     // rev: grouped by row, src = col
        int p1 = atomicAdd(&cur[k1 >> 7], 1);
        binned[p1] = make_uint2((unsigned)((k1 & 127) | (r << 7)), wb);
        int p2 = atomicAdd(&cur[k2 >> 7], 1);
        binned[p2] = make_uint2((unsigned)((k2 & 127) | (c << 7)), wb);
    }
}

// ---------------------------------------------------------------------------
// Pass B: per-bin counting sort (one block per bin, 128 keys/bin).
// Also computes weighted-degree sums -> inv[key] = 1/deg, and off[key].
// inv[key<N] = 1/deg_in[key] (= inv_i), inv[key>=N] = 1/deg_out[key-N] (= inv_o).
// ---------------------------------------------------------------------------
__global__ __launch_bounds__(256) void k_sortbin(const uint2* __restrict__ binned,
                                                 const int* __restrict__ scanA,
                                                 const int* __restrict__ bsum,
                                                 int* __restrict__ csr,
                                                 int* __restrict__ off,
                                                 float* __restrict__ inv) {
    __shared__ int cnt[128];
    __shared__ int sc[128];
    __shared__ int cur[128];
    __shared__ float deg[128];
    int tid = threadIdx.x;
    int b   = blockIdx.x;
    int i0 = b * NBLK_A;
    int base = scanA[i0] + bsum[i0 >> 8];
    int end;
    if (b + 1 < NBIN) {
        int i1 = (b + 1) * NBLK_A;
        end = scanA[i1] + bsum[i1 >> 8];
    } else end = TOT;
    if (tid < 128) { cnt[tid] = 0; deg[tid] = 0.0f; }
    __syncthreads();
    for (int i = base + tid; i < end; i += 256) {
        uint2 it = binned[i];
        int kl = it.x & 127;
        atomicAdd(&cnt[kl], 1);
        atomicAdd(&deg[kl], __uint_as_float(it.y));
    }
    __syncthreads();
    if (tid < 128) sc[tid] = cnt[tid];
    __syncthreads();
    for (int d = 1; d < 128; d <<= 1) {
        int t = (tid >= d && tid < 128) ? sc[tid - d] : 0;
        __syncthreads();
        if (tid < 128) sc[tid] += t;
        __syncthreads();
    }
    if (tid < 128) cur[tid] = sc[tid] - cnt[tid];   // exclusive
    __syncthreads();
    for (int i = base + tid; i < end; i += 256) {
        uint2 it = binned[i];
        int kl = it.x & 127;
        int pos = atomicAdd(&cur[kl], 1);
        csr[base + pos] = (int)(it.x >> 7);
    }
    if (tid < 128) {
        int key = (b << 7) + tid;
        off[key] = base + sc[tid] - cnt[tid];
        inv[key] = 1.0f / deg[tid];                  // inf for deg 0: never gathered
    }
    // keys 100000..100095 (bin 781 padding) get off = TOT -> valid sentinel.
}

// ---------------------------------------------------------------------------
// Pre-scaled bf16 gather source tables (after CSR build; needs inv):
//   Xso[v] = inv_o[v]*X[v]  (fwd table),  Xsi[v] = inv_i[v]*X[v]  (rev table)
// ---------------------------------------------------------------------------
__global__ __launch_bounds__(256) void k_xbf(const float* __restrict__ X,
                                             const float* __restrict__ inv,
                                             ushort* __restrict__ Xso,
                                             ushort* __restrict__ Xsi) {
    int t = blockIdx.x * 256 + threadIdx.x;
    if (t * 4 >= (int)NF) return;
    int v = (t * 4) >> 5;                     // F_IN = 32, 4 | 32
    float so = inv[N_NODES + v];              // inv_o
    float si = inv[v];                        // inv_i
    float4 val = *(const float4*)&X[t * 4];
    ushort4 a, b;
    a.x = f2bf(val.x * so); a.y = f2bf(val.y * so);
    a.z = f2bf(val.z * so); a.w = f2bf(val.w * so);
    b.x = f2bf(val.x * si); b.y = f2bf(val.y * si);
    b.z = f2bf(val.z * si); b.w = f2bf(val.w * si);
    *(ushort4*)&Xso[t * 4] = a;
    *(ushort4*)&Xsi[t * 4] = b;
}

// ---------------------------------------------------------------------------
// Gather propagation: plain sum over pre-scaled bf16 tables. No coefficient
// gather, no atomics. Chain per edge: csr[j] -> 64B line -> add. Unroll 4.
// Direction-split XCD swizzle keeps each XCD's working set to one 3.2MB table.
// STEP 1: writes raw bf16 (for k_final) + pre-scaled bf16 (for step 2).
// STEP 2: writes fp32.
// ---------------------------------------------------------------------------
template<int STEP>
__global__ __launch_bounds__(256) void k_gather(const int* __restrict__ off,
                                                const int* __restrict__ csr,
                                                const float* __restrict__ inv,
                                                const ushort* __restrict__ hs_fwd,
                                                const ushort* __restrict__ hs_rev,
                                                ushort* __restrict__ raw_fwd,
                                                ushort* __restrict__ raw_rev,
                                                ushort* __restrict__ scl_fwd,
                                                ushort* __restrict__ scl_rev,
                                                float* __restrict__ f32_fwd,
                                                float* __restrict__ f32_rev) {
    int g    = blockIdx.x;
    int xcd  = g & 7;
    int slot = g >> 3;
    bool fwd = xcd < 4;
    int grp  = slot * 4 + (xcd & 3);
    if (grp >= NGRP) return;
    int kl  = threadIdx.x >> 5;
    int f   = threadIdx.x & 31;
    int key = grp * 8 + kl;                   // node id within direction
    int idx = fwd ? key : (N_NODES + key);
    const ushort* hs = fwd ? hs_fwd : hs_rev;
    int beg = off[idx];
    int end = off[idx + 1];
    float acc = 0.0f;
    int j = beg;
    for (; j + 3 < end; j += 4) {
        int s0 = csr[j], s1 = csr[j + 1], s2 = csr[j + 2], s3 = csr[j + 3];
        float h0 = bf2f(hs[s0 * F_IN + f]);
        float h1 = bf2f(hs[s1 * F_IN + f]);
        float h2 = bf2f(hs[s2 * F_IN + f]);
        float h3 = bf2f(hs[s3 * F_IN + f]);
        acc += h0; acc += h1; acc += h2; acc += h3;
    }
    for (; j < end; ++j)
        acc += bf2f(hs[csr[j] * F_IN + f]);

    if (STEP == 1) {
        // next-step table scale: fwd node v -> inv_o[v] = inv[N+v]; rev -> inv_i[v] = inv[v]
        float sc = fwd ? inv[N_NODES + key] : inv[key];
        (fwd ? raw_fwd : raw_rev)[key * F_IN + f] = f2bf(acc);
        (fwd ? scl_fwd : scl_rev)[key * F_IN + f] = f2bf(acc * sc);
    } else {
        (fwd ? f32_fwd : f32_rev)[key * F_IN + f] = acc;
    }
}

// ---------------------------------------------------------------------------
// Build bf16 transposed weight Wt[o][k], o in [0,128): z cols then h cols.
// Source layout (2,3,96,64); rows 32..95 dead (H0==0).
// ---------------------------------------------------------------------------
__global__ __launch_bounds__(256) void k_prep(const float* __restrict__ wz,
                                              const float* __restrict__ wh,
                                              ushort* __restrict__ Wt) {
    int tid = blockIdx.x * blockDim.x + threadIdx.x;
    if (tid >= 128 * C_FEAT) return;
    int o = tid / C_FEAT;
    int k = tid % C_FEAT;
    int seg = k >> 5;
    int cc  = k & 31;
    const float* src = (o < 64) ? wz : wh;
    int oo = o & 63;
    float val;
    if (seg == 0)      val = src[(0 * 96 + cc) * 64 + oo] + src[(3 * 96 + cc) * 64 + oo];
    else if (seg == 1) val = src[(1 * 96 + cc) * 64 + oo];
    else if (seg == 2) val = src[(4 * 96 + cc) * 64 + oo];
    else if (seg == 3) val = src[(2 * 96 + cc) * 64 + oo];
    else               val = src[(5 * 96 + cc) * 64 + oo];
    Wt[tid] = f2bf(val);
}

// ---------------------------------------------------------------------------
// MFMA epilogue: [32 nodes x 160] x [160 x 128], B in registers, A direct
// from global. In-register gating; LDS only for relu'd H -> 64x12 head.
// ---------------------------------------------------------------------------
__global__ __launch_bounds__(256, 3) void k_final(
        const float* __restrict__ X,
        const ushort* __restrict__ Tx1o,
        const ushort* __restrict__ Tx1i,
        const float* __restrict__ P2o,
        const float* __restrict__ P2i,
        const ushort* __restrict__ Wt,
        const float* __restrict__ bz,
        const float* __restrict__ bh,
        const float* __restrict__ wlin,
        const float* __restrict__ blin,
        float* __restrict__ out) {
    __shared__ float r_lds[32][66];                    // 8448 B total LDS
    int tid   = threadIdx.x;
    int node0 = blockIdx.x * 32;
    int w  = tid >> 6;
    int l  = tid & 63;
    int lr = l & 15;
    int lg = l >> 4;
    int rt = w & 1;             // row tile (16 nodes)
    int cb = (w >> 1) * 32;     // col base within the 64 z (and 64 h) cols

    // --- B fragments in registers: t in {z-ct0, z-ct1, h-ct0, h-ct1} ---
    s16x8 bf[4][5];
#pragma unroll
    for (int t = 0; t < 4; ++t) {
        int col = cb + (t & 1) * 16 + lr + ((t >> 1) ? 64 : 0);
        const ushort* wp = Wt + col * C_FEAT + lg * 8;
#pragma unroll
        for (int kb = 0; kb < 5; ++kb)
            bf[t][kb] = *(const s16x8*)(wp + kb * 32);
    }

    // --- A fragments (row clamped; tail rows masked at write) ---
    int row = node0 + rt * 16 + lr;
    if (row >= N_NODES) row = N_NODES - 1;
    int rbase = row * F_IN + lg * 8;
    float4 x0 = *(const float4*)&X[rbase],   x1 = *(const float4*)&X[rbase + 4];
    float4 p0 = *(const float4*)&P2o[rbase], p1 = *(const float4*)&P2o[rbase + 4];
    float4 q0 = *(const float4*)&P2i[rbase], q1 = *(const float4*)&P2i[rbase + 4];
    s16x8 a[5];
    a[0] = pack8(x0, x1);
    a[1] = *(const s16x8*)&Tx1o[rbase];
    a[2] = *(const s16x8*)&Tx1i[rbase];
    float4 t3l = make_float4(2.f*p0.x-x0.x, 2.f*p0.y-x0.y, 2.f*p0.z-x0.z, 2.f*p0.w-x0.w);
    float4 t3h = make_float4(2.f*p1.x-x1.x, 2.f*p1.y-x1.y, 2.f*p1.z-x1.z, 2.f*p1.w-x1.w);
    float4 t4l = make_float4(2.f*q0.x-x0.x, 2.f*q0.y-x0.y, 2.f*q0.z-x0.z, 2.f*q0.w-x0.w);
    float4 t4h = make_float4(2.f*q1.x-x1.x, 2.f*q1.y-x1.y, 2.f*q1.z-x1.z, 2.f*q1.w-x1.w);
    a[3] = pack8(t3l, t3h);
    a[4] = pack8(t4l, t4h);

    // --- MFMA: 4 accs x 5 K-blocks ---
    f32x4 acc[4] = {};
#pragma unroll
    for (int kb = 0; kb < 5; ++kb) {
        acc[0] = __builtin_amdgcn_mfma_f32_16x16x32_bf16(a[kb], bf[0][kb], acc[0], 0, 0, 0);
        acc[1] = __builtin_amdgcn_mfma_f32_16x16x32_bf16(a[kb], bf[1][kb], acc[1], 0, 0, 0);
        acc[2] = __builtin_amdgcn_mfma_f32_16x16x32_bf16(a[kb], bf[2][kb], acc[2], 0, 0, 0);
        acc[3] = __builtin_amdgcn_mfma_f32_16x16x32_bf16(a[kb], bf[3][kb], acc[3], 0, 0, 0);
    }

    // --- in-register gating; D layout: col = lane&15, row = lg*4 + q ---
#pragma unroll
    for (int ct = 0; ct < 2; ++ct) {
        int o = cb + ct * 16 + lr;
        float bzv = bz[o];
        float bhv = bh[o];
#pragma unroll
        for (int qq = 0; qq < 4; ++qq) {
            float zp = acc[ct][qq] + bzv;
            float hp = acc[2 + ct][qq] + bhv;
            float z  = 1.0f / (1.0f + __expf(-zp));
            float e2 = __expf(2.0f * hp);
            float th = 1.0f - 2.0f / (e2 + 1.0f);    // tanh(hp)
            r_lds[rt * 16 + lg * 4 + qq][o] = fmaxf((1.0f - z) * th, 0.0f);
        }
    }
    __syncthreads();

    // --- 64x12 head ---
    for (int i = tid; i < 32 * PERIODS; i += 256) {
        int n = i / PERIODS;
        int p = i % PERIODS;
        int v = node0 + n;
        if (v < N_NODES) {
            float acc2 = blin[p];
#pragma unroll
            for (int oo = 0; oo < F_OUT; ++oo)
                acc2 = fmaf(r_lds[n][oo], wlin[oo * PERIODS + p], acc2);
            out[v * PERIODS + p] = acc2;
        }
    }
}

// ---------------------------------------------------------------------------
extern "C" void kernel_launch(void* const* d_in, const int* in_sizes, int n_in,
                              void* d_out, int out_size, void* d_ws, size_t ws_size,
                              hipStream_t stream) {
    const float* x    = (const float*)d_in[0];
    const int*   ei   = (const int*)d_in[1];
    const float* ew   = (const float*)d_in[2];
    const float* wz   = (const float*)d_in[3];
    const float* bz   = (const float*)d_in[4];
    // d_in[5], d_in[6] = w_r, b_r : provably unused (H0 == 0)
    const float* wh   = (const float*)d_in[7];
    const float* bh   = (const float*)d_in[8];
    const float* wlin = (const float*)d_in[9];
    const float* blin = (const float*)d_in[10];

    // workspace layout — all write-before-read; no memset. Xso/Xsi alias the
    // binned buffer (dead after k_sortbin; k_xbf runs after it).
    int*    histA  = (int*)d_ws;                       // [100096]
    int*    scanA  = histA + SCANA_N;                  // [100096]
    int*    bsum   = scanA + SCANA_N;                  // [512]
    uint2*  binned = (uint2*)(bsum + 512);             // [1.6M] 12.8 MB
    ushort* Xso    = (ushort*)binned;                  // [NF] aliases binned
    ushort* Xsi    = Xso + NF;                         // [NF] aliases binned (6.4 MB < 12.8)
    int*    csr    = (int*)(binned + TOT);             // [1.6M]
    int*    off    = csr + TOT;                        // [100100]
    float*  inv    = (float*)(off + 100100);           // [100096]
    ushort* T1o_b  = (ushort*)(inv + SCANA_N);         // raw bf16 Tx1 (k_final)
    ushort* T1i_b  = T1o_b + NF;
    ushort* T1o_s  = T1i_b + NF;                       // pre-scaled bf16 (step 2)
    ushort* T1i_s  = T1o_s + NF;
    float*  P2o    = (float*)(T1i_s + NF);             // fp32
    float*  P2i    = P2o + NF;
    ushort* Wt     = (ushort*)(P2i + NF);              // [128*160] bf16

    k_prep<<<(128 * C_FEAT + 255) / 256, 256, 0, stream>>>(wz, wh, Wt);

    // CSR build: histogram -> scan -> multi-split -> per-bin counting sort
    k_histA<<<NBLK_A, 256, 0, stream>>>(ei, histA);
    k_scan1<<<SCANA_NB, 256, 0, stream>>>(histA, scanA, bsum);
    k_scan2<<<1, 512, 0, stream>>>(bsum);
    k_binA<<<NBLK_A, 256, 0, stream>>>(ei, ew, scanA, bsum, binned);
    k_sortbin<<<NBIN, 256, 0, stream>>>(binned, scanA, bsum, csr, off, inv);

    // pre-scaled X tables (needs inv; binned now dead)
    k_xbf<<<((int)NF / 4 + 255) / 256, 256, 0, stream>>>(x, inv, Xso, Xsi);

    int ggrid = 8 * ((NGRP + 3) / 4);   // 12504 blocks, direction-split swizzle
    // step 1: Tx1 = prop(X): raw bf16 + pre-scaled bf16 outputs
    k_gather<1><<<ggrid, 256, 0, stream>>>(off, csr, inv, Xso, Xsi,
                                           T1o_b, T1i_b, T1o_s, T1i_s,
                                           nullptr, nullptr);
    // step 2: P2 = prop(Tx1_s): fp32 outputs; Tx2 = 2*P2 - X in k_final
    k_gather<2><<<ggrid, 256, 0, stream>>>(off, csr, inv, T1o_s, T1i_s,
                                           nullptr, nullptr, nullptr, nullptr,
                                           P2o, P2i);

    k_final<<<(N_NODES + 31) / 32, 256, 0, stream>>>(x, T1o_b, T1i_b, P2o, P2i, Wt,
                                                     bz, bh, wlin, blin, (float*)d_out);
}

// Round 8
// 133.168 us; speedup vs baseline: 4.1732x; 1.1839x over previous
//
#include <hip/hip_runtime.h>

#define N_NODES 50000
#define N_EDGES 800000
#define F_IN    32
#define F_OUT   64
#define PERIODS 12
#define C_FEAT  160   // [X, Tx1o, Tx1i, Tx2o, Tx2i] each 32 channels

#define NKEY    (2 * N_NODES)    // 100000 combined keys: fwd=col, rev=N+row
#define NBIN    782              // ceil(100000/128) — 128 keys per bin
#define NBLK_A  128
#define EPB     (N_EDGES / NBLK_A)   // 6250 edges per A-block (exact)
#define TOT     (2 * N_EDGES)        // 1.6M CSR entries
#define SCANA_N (NBIN * NBLK_A)      // 100096 = 391*256 exactly
#define SCANA_NB 391
#define KPB     16                   // keys per gather block (16-lane groups)
#define NBLK_DIR (N_NODES / KPB)     // 3125 gather blocks per direction
#define NF      ((size_t)N_NODES * F_IN)

typedef __attribute__((ext_vector_type(8))) short s16x8;
typedef __attribute__((ext_vector_type(4))) float f32x4;

static __device__ __forceinline__ ushort f2bf(float f) {
    unsigned u = __float_as_uint(f);
    unsigned r = (u + 0x7FFFu + ((u >> 16) & 1u)) >> 16;   // RNE
    return (ushort)r;
}
static __device__ __forceinline__ float bf2f(ushort u) {
    return __uint_as_float((unsigned)u << 16);
}
static __device__ __forceinline__ float bfLO(unsigned h) {   // low bf16 channel
    return __uint_as_float(h << 16);
}
static __device__ __forceinline__ float bfHI(unsigned h) {   // high bf16 channel
    return __uint_as_float(h & 0xffff0000u);
}

static __device__ __forceinline__ s16x8 pack8(float4 lo, float4 hi) {
    s16x8 r;
    r[0] = (short)f2bf(lo.x); r[1] = (short)f2bf(lo.y);
    r[2] = (short)f2bf(lo.z); r[3] = (short)f2bf(lo.w);
    r[4] = (short)f2bf(hi.x); r[5] = (short)f2bf(hi.y);
    r[6] = (short)f2bf(hi.z); r[7] = (short)f2bf(hi.w);
    return r;
}

// ---------------------------------------------------------------------------
// Pass A1: per-block LDS histogram of combined keys into 782 coarse bins.
// ---------------------------------------------------------------------------
__global__ __launch_bounds__(256) void k_histA(const int* __restrict__ ei,
                                               int* __restrict__ hist) {
    __shared__ int h[NBIN];
    int tid = threadIdx.x, blk = blockIdx.x;
    for (int i = tid; i < NBIN; i += 256) h[i] = 0;
    __syncthreads();
    int e0 = blk * EPB;
    for (int i = tid; i < EPB; i += 256) {
        int e = e0 + i;
        int r = ei[e];
        int c = ei[N_EDGES + e];
        atomicAdd(&h[c >> 7], 1);
        atomicAdd(&h[(N_NODES + r) >> 7], 1);
    }
    __syncthreads();
    for (int i = tid; i < NBIN; i += 256) hist[i * NBLK_A + blk] = h[i];
}

// ---------------------------------------------------------------------------
// Exclusive scan of hist[SCANA_N]; bsum folded in by consumers.
// ---------------------------------------------------------------------------
__global__ __launch_bounds__(256) void k_scan1(const int* __restrict__ cnt,
                                               int* __restrict__ scanA,
                                               int* __restrict__ bsum) {
    __shared__ int lds[256];
    int g = blockIdx.x * 256 + threadIdx.x;
    int v = (g < SCANA_N) ? cnt[g] : 0;
    int orig = v;
    lds[threadIdx.x] = v;
    __syncthreads();
    for (int d = 1; d < 256; d <<= 1) {
        int t = (threadIdx.x >= d) ? lds[threadIdx.x - d] : 0;
        __syncthreads();
        lds[threadIdx.x] += t;
        __syncthreads();
    }
    if (g < SCANA_N) scanA[g] = lds[threadIdx.x] - orig;   // exclusive, block-local
    if (threadIdx.x == 255) bsum[blockIdx.x] = lds[threadIdx.x];
}

__global__ __launch_bounds__(512) void k_scan2(int* __restrict__ bsum) {
    __shared__ int lds[512];
    int t = threadIdx.x;
    int v = (t < SCANA_NB) ? bsum[t] : 0;
    int orig = v;
    lds[t] = v;
    __syncthreads();
    for (int d = 1; d < 512; d <<= 1) {
        int x = (t >= d) ? lds[t - d] : 0;
        __syncthreads();
        lds[t] += x;
        __syncthreads();
    }
    if (t < SCANA_NB) bsum[t] = lds[t] - orig;             // exclusive
}

// ---------------------------------------------------------------------------
// Pass A3: multi-split — place 8B items (key_low7 | src<<7, w) into bins.
// ---------------------------------------------------------------------------
__global__ __launch_bounds__(256) void k_binA(const int* __restrict__ ei,
                                              const float* __restrict__ ew,
                                              const int* __restrict__ scanA,
                                              const int* __restrict__ bsum,
                                              uint2* __restrict__ binned) {
    __shared__ int cur[NBIN];
    int tid = threadIdx.x, blk = blockIdx.x;
    for (int i = tid; i < NBIN; i += 256) {
        int idx = i * NBLK_A + blk;
        cur[i] = scanA[idx] + bsum[idx >> 8];
    }
    __syncthreads();
    int e0 = blk * EPB;
    for (int i = tid; i < EPB; i += 256) {
        int e = e0 + i;
        int r = ei[e];
        int c = ei[N_EDGES + e];
        unsigned wb = __float_as_uint(ew[e]);
        int k1 = c;               // fwd: grouped by col, src = row
        int k2 = N_NODES + r;     // rev: grouped by row, src = col
        int p1 = atomicAdd(&cur[k1 >> 7], 1);
        binned[p1] = make_uint2((unsigned)((k1 & 127) | (r << 7)), wb);
        int p2 = atomicAdd(&cur[k2 >> 7], 1);
        binned[p2] = make_uint2((unsigned)((k2 & 127) | (c << 7)), wb);
    }
}

// ---------------------------------------------------------------------------
// Pass B: per-bin counting sort (one block per bin, 128 keys/bin), 2 items
// per thread per pass. Also computes degree sums -> inv[key], and off[key].
// inv[key<N] = inv_i, inv[key>=N] = inv_o.
// ---------------------------------------------------------------------------
__global__ __launch_bounds__(256) void k_sortbin(const uint2* __restrict__ binned,
                                                 const int* __restrict__ scanA,
                                                 const int* __restrict__ bsum,
                                                 int* __restrict__ csr,
                                                 int* __restrict__ off,
                                                 float* __restrict__ inv) {
    __shared__ int cnt[128];
    __shared__ int sc[128];
    __shared__ int cur[128];
    __shared__ float deg[128];
    int tid = threadIdx.x;
    int b   = blockIdx.x;
    int i0 = b * NBLK_A;
    int base = scanA[i0] + bsum[i0 >> 8];
    int end;
    if (b + 1 < NBIN) {
        int i1 = (b + 1) * NBLK_A;
        end = scanA[i1] + bsum[i1 >> 8];
    } else end = TOT;
    if (tid < 128) { cnt[tid] = 0; deg[tid] = 0.0f; }
    __syncthreads();
    for (int i = base + 2 * tid; i < end; i += 512) {
        uint2 it = binned[i];
        int kl = it.x & 127;
        atomicAdd(&cnt[kl], 1);
        atomicAdd(&deg[kl], __uint_as_float(it.y));
        if (i + 1 < end) {
            uint2 it2 = binned[i + 1];
            int kl2 = it2.x & 127;
            atomicAdd(&cnt[kl2], 1);
            atomicAdd(&deg[kl2], __uint_as_float(it2.y));
        }
    }
    __syncthreads();
    if (tid < 128) sc[tid] = cnt[tid];
    __syncthreads();
    for (int d = 1; d < 128; d <<= 1) {
        int t = (tid >= d && tid < 128) ? sc[tid - d] : 0;
        __syncthreads();
        if (tid < 128) sc[tid] += t;
        __syncthreads();
    }
    if (tid < 128) cur[tid] = sc[tid] - cnt[tid];   // exclusive
    __syncthreads();
    for (int i = base + 2 * tid; i < end; i += 512) {
        uint2 it = binned[i];
        int kl = it.x & 127;
        int pos = atomicAdd(&cur[kl], 1);
        csr[base + pos] = (int)(it.x >> 7);
        if (i + 1 < end) {
            uint2 it2 = binned[i + 1];
            int kl2 = it2.x & 127;
            int pos2 = atomicAdd(&cur[kl2], 1);
            csr[base + pos2] = (int)(it2.x >> 7);
        }
    }
    if (tid < 128) {
        int key = (b << 7) + tid;
        off[key] = base + sc[tid] - cnt[tid];
        inv[key] = 1.0f / deg[tid];                  // inf for deg 0: never gathered
    }
    // keys 100000..100095 (bin 781 padding) get off = TOT -> valid sentinel.
}

// ---------------------------------------------------------------------------
// Pre-scaled bf16 gather source tables (after CSR build; needs inv):
//   Xso[v] = inv_o[v]*X[v]  (fwd table),  Xsi[v] = inv_i[v]*X[v]  (rev table)
// ---------------------------------------------------------------------------
__global__ __launch_bounds__(256) void k_xbf(const float* __restrict__ X,
                                             const float* __restrict__ inv,
                                             ushort* __restrict__ Xso,
                                             ushort* __restrict__ Xsi) {
    int t = blockIdx.x * 256 + threadIdx.x;
    if (t * 4 >= (int)NF) return;
    int v = (t * 4) >> 5;                     // F_IN = 32, 4 | 32
    float so = inv[N_NODES + v];              // inv_o
    float si = inv[v];                        // inv_i
    float4 val = *(const float4*)&X[t * 4];
    ushort4 a, b;
    a.x = f2bf(val.x * so); a.y = f2bf(val.y * so);
    a.z = f2bf(val.z * so); a.w = f2bf(val.w * so);
    b.x = f2bf(val.x * si); b.y = f2bf(val.y * si);
    b.z = f2bf(val.z * si); b.w = f2bf(val.w * si);
    *(ushort4*)&Xso[t * 4] = a;
    *(ushort4*)&Xsi[t * 4] = b;
}

// ---------------------------------------------------------------------------
// Gather propagation: plain sum over pre-scaled bf16 tables (uint = 2 ch).
// 16-lane key-groups (4 keys/wave), unroll 8 (+4 +tail) -> up to 32 lines
// in flight per wave. Direction-split XCD swizzle (fwd on XCD 0-3, rev 4-7).
// STEP 1: writes raw bf16 (k_final) + pre-scaled bf16 (step 2); STEP 2: fp32.
// ---------------------------------------------------------------------------
template<int STEP>
__global__ __launch_bounds__(256) void k_gather(const int* __restrict__ off,
                                                const int* __restrict__ csr,
                                                const float* __restrict__ inv,
                                                const unsigned* __restrict__ hs_fwd,
                                                const unsigned* __restrict__ hs_rev,
                                                unsigned* __restrict__ raw_fwd,
                                                unsigned* __restrict__ raw_rev,
                                                unsigned* __restrict__ scl_fwd,
                                                unsigned* __restrict__ scl_rev,
                                                float2* __restrict__ f32_fwd,
                                                float2* __restrict__ f32_rev) {
    int g    = blockIdx.x;
    int xcd  = g & 7;
    int slot = g >> 3;
    bool fwd = xcd < 4;
    int blk  = slot * 4 + (xcd & 3);          // block index within direction
    if (blk >= NBLK_DIR) return;
    int kg  = threadIdx.x >> 4;               // key group 0..15
    int f2  = threadIdx.x & 15;               // channel pair
    int key = blk * KPB + kg;
    int idx = fwd ? key : (N_NODES + key);
    const unsigned* hs = fwd ? hs_fwd : hs_rev;
    int beg = off[idx];
    int end = off[idx + 1];
    float aL0 = 0.f, aH0 = 0.f, aL1 = 0.f, aH1 = 0.f;
    int j = beg;
    for (; j + 7 < end; j += 8) {
        int s0 = csr[j],     s1 = csr[j + 1], s2 = csr[j + 2], s3 = csr[j + 3];
        int s4 = csr[j + 4], s5 = csr[j + 5], s6 = csr[j + 6], s7 = csr[j + 7];
        unsigned h0 = hs[s0 * 16 + f2], h1 = hs[s1 * 16 + f2];
        unsigned h2 = hs[s2 * 16 + f2], h3 = hs[s3 * 16 + f2];
        unsigned h4 = hs[s4 * 16 + f2], h5 = hs[s5 * 16 + f2];
        unsigned h6 = hs[s6 * 16 + f2], h7 = hs[s7 * 16 + f2];
        aL0 += bfLO(h0); aH0 += bfHI(h0); aL1 += bfLO(h1); aH1 += bfHI(h1);
        aL0 += bfLO(h2); aH0 += bfHI(h2); aL1 += bfLO(h3); aH1 += bfHI(h3);
        aL0 += bfLO(h4); aH0 += bfHI(h4); aL1 += bfLO(h5); aH1 += bfHI(h5);
        aL0 += bfLO(h6); aH0 += bfHI(h6); aL1 += bfLO(h7); aH1 += bfHI(h7);
    }
    for (; j + 3 < end; j += 4) {
        int s0 = csr[j],     s1 = csr[j + 1], s2 = csr[j + 2], s3 = csr[j + 3];
        unsigned h0 = hs[s0 * 16 + f2], h1 = hs[s1 * 16 + f2];
        unsigned h2 = hs[s2 * 16 + f2], h3 = hs[s3 * 16 + f2];
        aL0 += bfLO(h0); aH0 += bfHI(h0); aL1 += bfLO(h1); aH1 += bfHI(h1);
        aL0 += bfLO(h2); aH0 += bfHI(h2); aL1 += bfLO(h3); aH1 += bfHI(h3);
    }
    for (; j < end; ++j) {
        unsigned h = hs[csr[j] * 16 + f2];
        aL0 += bfLO(h); aH0 += bfHI(h);
    }
    float aL = aL0 + aL1;
    float aH = aH0 + aH1;

    if (STEP == 1) {
        // next-step table scale: fwd node v -> inv_o[v] = inv[N+v]; rev -> inv_i[v]
        float sc = fwd ? inv[N_NODES + key] : inv[key];
        unsigned raw = ((unsigned)f2bf(aH) << 16) | f2bf(aL);
        unsigned scl = ((unsigned)f2bf(aH * sc) << 16) | f2bf(aL * sc);
        (fwd ? raw_fwd : raw_rev)[key * 16 + f2] = raw;
        (fwd ? scl_fwd : scl_rev)[key * 16 + f2] = scl;
    } else {
        (fwd ? f32_fwd : f32_rev)[key * 16 + f2] = make_float2(aL, aH);
    }
}

// ---------------------------------------------------------------------------
// Build bf16 transposed weight Wt[o][k], o in [0,128): z cols then h cols.
// Source layout (2,3,96,64); rows 32..95 dead (H0==0).
// ---------------------------------------------------------------------------
__global__ __launch_bounds__(256) void k_prep(const float* __restrict__ wz,
                                              const float* __restrict__ wh,
                                              ushort* __restrict__ Wt) {
    int tid = blockIdx.x * blockDim.x + threadIdx.x;
    if (tid >= 128 * C_FEAT) return;
    int o = tid / C_FEAT;
    int k = tid % C_FEAT;
    int seg = k >> 5;
    int cc  = k & 31;
    const float* src = (o < 64) ? wz : wh;
    int oo = o & 63;
    float val;
    if (seg == 0)      val = src[(0 * 96 + cc) * 64 + oo] + src[(3 * 96 + cc) * 64 + oo];
    else if (seg == 1) val = src[(1 * 96 + cc) * 64 + oo];
    else if (seg == 2) val = src[(4 * 96 + cc) * 64 + oo];
    else if (seg == 3) val = src[(2 * 96 + cc) * 64 + oo];
    else               val = src[(5 * 96 + cc) * 64 + oo];
    Wt[tid] = f2bf(val);
}

// ---------------------------------------------------------------------------
// MFMA epilogue: [32 nodes x 160] x [160 x 128], B in registers, A direct
// from global. In-register gating; LDS only for relu'd H -> 64x12 head.
// ---------------------------------------------------------------------------
__global__ __launch_bounds__(256, 3) void k_final(
        const float* __restrict__ X,
        const ushort* __restrict__ Tx1o,
        const ushort* __restrict__ Tx1i,
        const float* __restrict__ P2o,
        const float* __restrict__ P2i,
        const ushort* __restrict__ Wt,
        const float* __restrict__ bz,
        const float* __restrict__ bh,
        const float* __restrict__ wlin,
        const float* __restrict__ blin,
        float* __restrict__ out) {
    __shared__ float r_lds[32][66];                    // 8448 B total LDS
    int tid   = threadIdx.x;
    int node0 = blockIdx.x * 32;
    int w  = tid >> 6;
    int l  = tid & 63;
    int lr = l & 15;
    int lg = l >> 4;
    int rt = w & 1;             // row tile (16 nodes)
    int cb = (w >> 1) * 32;     // col base within the 64 z (and 64 h) cols

    // --- B fragments in registers: t in {z-ct0, z-ct1, h-ct0, h-ct1} ---
    s16x8 bf[4][5];
#pragma unroll
    for (int t = 0; t < 4; ++t) {
        int col = cb + (t & 1) * 16 + lr + ((t >> 1) ? 64 : 0);
        const ushort* wp = Wt + col * C_FEAT + lg * 8;
#pragma unroll
        for (int kb = 0; kb < 5; ++kb)
            bf[t][kb] = *(const s16x8*)(wp + kb * 32);
    }

    // --- A fragments (row clamped; tail rows masked at write) ---
    int row = node0 + rt * 16 + lr;
    if (row >= N_NODES) row = N_NODES - 1;
    int rbase = row * F_IN + lg * 8;
    float4 x0 = *(const float4*)&X[rbase],   x1 = *(const float4*)&X[rbase + 4];
    float4 p0 = *(const float4*)&P2o[rbase], p1 = *(const float4*)&P2o[rbase + 4];
    float4 q0 = *(const float4*)&P2i[rbase], q1 = *(const float4*)&P2i[rbase + 4];
    s16x8 a[5];
    a[0] = pack8(x0, x1);
    a[1] = *(const s16x8*)&Tx1o[rbase];
    a[2] = *(const s16x8*)&Tx1i[rbase];
    float4 t3l = make_float4(2.f*p0.x-x0.x, 2.f*p0.y-x0.y, 2.f*p0.z-x0.z, 2.f*p0.w-x0.w);
    float4 t3h = make_float4(2.f*p1.x-x1.x, 2.f*p1.y-x1.y, 2.f*p1.z-x1.z, 2.f*p1.w-x1.w);
    float4 t4l = make_float4(2.f*q0.x-x0.x, 2.f*q0.y-x0.y, 2.f*q0.z-x0.z, 2.f*q0.w-x0.w);
    float4 t4h = make_float4(2.f*q1.x-x1.x, 2.f*q1.y-x1.y, 2.f*q1.z-x1.z, 2.f*q1.w-x1.w);
    a[3] = pack8(t3l, t3h);
    a[4] = pack8(t4l, t4h);

    // --- MFMA: 4 accs x 5 K-blocks ---
    f32x4 acc[4] = {};
#pragma unroll
    for (int kb = 0; kb < 5; ++kb) {
        acc[0] = __builtin_amdgcn_mfma_f32_16x16x32_bf16(a[kb], bf[0][kb], acc[0], 0, 0, 0);
        acc[1] = __builtin_amdgcn_mfma_f32_16x16x32_bf16(a[kb], bf[1][kb], acc[1], 0, 0, 0);
        acc[2] = __builtin_amdgcn_mfma_f32_16x16x32_bf16(a[kb], bf[2][kb], acc[2], 0, 0, 0);
        acc[3] = __builtin_amdgcn_mfma_f32_16x16x32_bf16(a[kb], bf[3][kb], acc[3], 0, 0, 0);
    }

    // --- in-register gating; D layout: col = lane&15, row = lg*4 + q ---
#pragma unroll
    for (int ct = 0; ct < 2; ++ct) {
        int o = cb + ct * 16 + lr;
        float bzv = bz[o];
        float bhv = bh[o];
#pragma unroll
        for (int qq = 0; qq < 4; ++qq) {
            float zp = acc[ct][qq] + bzv;
            float hp = acc[2 + ct][qq] + bhv;
            float z  = 1.0f / (1.0f + __expf(-zp));
            float e2 = __expf(2.0f * hp);
            float th = 1.0f - 2.0f / (e2 + 1.0f);    // tanh(hp)
            r_lds[rt * 16 + lg * 4 + qq][o] = fmaxf((1.0f - z) * th, 0.0f);
        }
    }
    __syncthreads();

    // --- 64x12 head ---
    for (int i = tid; i < 32 * PERIODS; i += 256) {
        int n = i / PERIODS;
        int p = i % PERIODS;
        int v = node0 + n;
        if (v < N_NODES) {
            float acc2 = blin[p];
#pragma unroll
            for (int oo = 0; oo < F_OUT; ++oo)
                acc2 = fmaf(r_lds[n][oo], wlin[oo * PERIODS + p], acc2);
            out[v * PERIODS + p] = acc2;
        }
    }
}

// ---------------------------------------------------------------------------
extern "C" void kernel_launch(void* const* d_in, const int* in_sizes, int n_in,
                              void* d_out, int out_size, void* d_ws, size_t ws_size,
                              hipStream_t stream) {
    const float* x    = (const float*)d_in[0];
    const int*   ei   = (const int*)d_in[1];
    const float* ew   = (const float*)d_in[2];
    const float* wz   = (const float*)d_in[3];
    const float* bz   = (const float*)d_in[4];
    // d_in[5], d_in[6] = w_r, b_r : provably unused (H0 == 0)
    const float* wh   = (const float*)d_in[7];
    const float* bh   = (const float*)d_in[8];
    const float* wlin = (const float*)d_in[9];
    const float* blin = (const float*)d_in[10];

    // workspace layout — all write-before-read; no memset. Xso/Xsi alias the
    // binned buffer (dead after k_sortbin; k_xbf runs after it).
    int*      histA  = (int*)d_ws;                     // [100096]
    int*      scanA  = histA + SCANA_N;                // [100096]
    int*      bsum   = scanA + SCANA_N;                // [512]
    uint2*    binned = (uint2*)(bsum + 512);           // [1.6M] 12.8 MB
    ushort*   Xso    = (ushort*)binned;                // [NF] aliases binned
    ushort*   Xsi    = Xso + NF;                       // [NF] aliases binned
    int*      csr    = (int*)(binned + TOT);           // [1.6M]
    int*      off    = csr + TOT;                      // [100100]
    float*    inv    = (float*)(off + 100100);         // [100096]
    ushort*   T1o_b  = (ushort*)(inv + SCANA_N);       // raw bf16 Tx1 (k_final)
    ushort*   T1i_b  = T1o_b + NF;
    ushort*   T1o_s  = T1i_b + NF;                     // pre-scaled bf16 (step 2)
    ushort*   T1i_s  = T1o_s + NF;
    float*    P2o    = (float*)(T1i_s + NF);           // fp32
    float*    P2i    = P2o + NF;
    ushort*   Wt     = (ushort*)(P2i + NF);            // [128*160] bf16

    k_prep<<<(128 * C_FEAT + 255) / 256, 256, 0, stream>>>(wz, wh, Wt);

    // CSR build: histogram -> scan -> multi-split -> per-bin counting sort
    k_histA<<<NBLK_A, 256, 0, stream>>>(ei, histA);
    k_scan1<<<SCANA_NB, 256, 0, stream>>>(histA, scanA, bsum);
    k_scan2<<<1, 512, 0, stream>>>(bsum);
    k_binA<<<NBLK_A, 256, 0, stream>>>(ei, ew, scanA, bsum, binned);
    k_sortbin<<<NBIN, 256, 0, stream>>>(binned, scanA, bsum, csr, off, inv);

    // pre-scaled X tables (needs inv; binned now dead)
    k_xbf<<<((int)NF / 4 + 255) / 256, 256, 0, stream>>>(x, inv, Xso, Xsi);

    int ggrid = 8 * ((NBLK_DIR + 3) / 4);   // 6256 blocks, direction-split swizzle
    // step 1: Tx1 = prop(X): raw bf16 + pre-scaled bf16 outputs
    k_gather<1><<<ggrid, 256, 0, stream>>>(off, csr, inv,
                                           (const unsigned*)Xso, (const unsigned*)Xsi,
                                           (unsigned*)T1o_b, (unsigned*)T1i_b,
                                           (unsigned*)T1o_s, (unsigned*)T1i_s,
                                           nullptr, nullptr);
    // step 2: P2 = prop(Tx1_s): fp32 outputs; Tx2 = 2*P2 - X in k_final
    k_gather<2><<<ggrid, 256, 0, stream>>>(off, csr, inv,
                                           (const unsigned*)T1o_s, (const unsigned*)T1i_s,
                                           nullptr, nullptr, nullptr, nullptr,
                                           (float2*)P2o, (float2*)P2i);

    k_final<<<(N_NODES + 31) / 32, 256, 0, stream>>>(x, T1o_b, T1i_b, P2o, P2i, Wt,
                                                     bz, bh, wlin, blin, (float*)d_out);
}